// Round 1
// baseline (3314.759 us; speedup 1.0000x reference)
//
#include <hip/hip_runtime.h>
#include <math.h>

#define CDIV(a,b) (((a)+(b)-1)/(b))

// ---------------- degree / dinv ----------------
__global__ void deg_count_kernel(const int* __restrict__ dst, float* __restrict__ deg, int E) {
    int e = blockIdx.x * blockDim.x + threadIdx.x;
    if (e < E) atomicAdd(&deg[dst[e]], 1.0f);
}

__global__ void dinv_kernel(float* __restrict__ deg, int N) {
    int i = blockIdx.x * blockDim.x + threadIdx.x;
    if (i < N) deg[i] = 1.0f / sqrtf(deg[i] + 1.0f);
}

// ---------------- generic fp32 GEMM: C = A[MxK] @ W[KxN] (+bias) (+relu) ----------------
// 16x16 threads, 64x64 tile, 4x4 per thread.
__global__ void gemm_kernel(const float* __restrict__ A, const float* __restrict__ W,
                            const float* __restrict__ bias, float* __restrict__ C,
                            int M, int K, int N, int do_relu) {
    __shared__ float As[64][17];
    __shared__ float Ws[16][65];
    const int tx = threadIdx.x;   // 0..15
    const int ty = threadIdx.y;   // 0..15
    const int tid = ty * 16 + tx;
    const int row0 = blockIdx.x * 64;
    const int col0 = blockIdx.y * 64;
    float acc[4][4] = {};
    for (int k0 = 0; k0 < K; k0 += 16) {
        #pragma unroll
        for (int i = 0; i < 4; ++i) {
            int idx = tid + i * 256;          // 0..1023
            int r = idx >> 4;
            int kk = idx & 15;
            int gr = row0 + r, gk = k0 + kk;
            As[r][kk] = (gr < M && gk < K) ? A[(size_t)gr * K + gk] : 0.0f;
        }
        #pragma unroll
        for (int i = 0; i < 4; ++i) {
            int idx = tid + i * 256;
            int kk = idx >> 6;                // 0..15
            int c = idx & 63;
            int gk = k0 + kk, gc = col0 + c;
            Ws[kk][c] = (gk < K && gc < N) ? W[(size_t)gk * N + gc] : 0.0f;
        }
        __syncthreads();
        #pragma unroll
        for (int kk = 0; kk < 16; ++kk) {
            float a[4], wv[4];
            #pragma unroll
            for (int i = 0; i < 4; ++i) a[i] = As[ty * 4 + i][kk];
            #pragma unroll
            for (int j = 0; j < 4; ++j) wv[j] = Ws[kk][tx * 4 + j];
            #pragma unroll
            for (int i = 0; i < 4; ++i)
                #pragma unroll
                for (int j = 0; j < 4; ++j)
                    acc[i][j] += a[i] * wv[j];
        }
        __syncthreads();
    }
    #pragma unroll
    for (int i = 0; i < 4; ++i) {
        int gr = row0 + ty * 4 + i;
        if (gr >= M) continue;
        #pragma unroll
        for (int j = 0; j < 4; ++j) {
            int gc = col0 + tx * 4 + j;
            if (gc >= N) continue;
            float v = acc[i][j];
            if (bias) v += bias[gc];
            if (do_relu) v = fmaxf(v, 0.0f);
            C[(size_t)gr * N + gc] = v;
        }
    }
}

// ---------------- GCN aggregation ----------------
template<int LOGF>
__global__ void self_init_kernel(const float* __restrict__ h, const float* __restrict__ dinv,
                                 float* __restrict__ agg, long long total) {
    long long idx = (long long)blockIdx.x * blockDim.x + threadIdx.x;
    if (idx >= total) return;
    int n = (int)(idx >> LOGF);
    float d = dinv[n];
    agg[idx] = h[idx] * d * d;
}

template<int LOGF>
__global__ void edge_scatter_kernel(const float* __restrict__ h, float* __restrict__ agg,
                                    const int* __restrict__ src, const int* __restrict__ dst,
                                    const float* __restrict__ dinv, long long total) {
    long long idx = (long long)blockIdx.x * blockDim.x + threadIdx.x;
    if (idx >= total) return;
    const int F = 1 << LOGF;
    int e = (int)(idx >> LOGF);
    int j = (int)(idx & (F - 1));
    int s = src[e], d = dst[e];
    float nrm = dinv[s] * dinv[d];
    atomicAdd(&agg[((size_t)d << LOGF) + j], h[((size_t)s << LOGF) + j] * nrm);
}

template<int LOGF>
__global__ void bias_res_relu_kernel(float* __restrict__ agg, const float* __restrict__ bias,
                                     const float* __restrict__ res, long long total) {
    long long idx = (long long)blockIdx.x * blockDim.x + threadIdx.x;
    if (idx >= total) return;
    const int F = 1 << LOGF;
    int j = (int)(idx & (F - 1));
    float v = agg[idx] + bias[j];
    if (res) v += res[idx];
    agg[idx] = fmaxf(v, 0.0f);
}

// ---------------- softmax over 256 cols, one wave per row ----------------
__global__ void softmax256_kernel(float* __restrict__ X, int M) {
    int row = blockIdx.x * 4 + (threadIdx.x >> 6);
    int lane = threadIdx.x & 63;
    if (row >= M) return;
    float* p = X + (size_t)row * 256;
    float v0 = p[lane], v1 = p[lane + 64], v2 = p[lane + 128], v3 = p[lane + 192];
    float m = fmaxf(fmaxf(v0, v1), fmaxf(v2, v3));
    for (int off = 32; off; off >>= 1) m = fmaxf(m, __shfl_xor(m, off));
    v0 = expf(v0 - m); v1 = expf(v1 - m); v2 = expf(v2 - m); v3 = expf(v3 - m);
    float s = v0 + v1 + v2 + v3;
    for (int off = 32; off; off >>= 1) s += __shfl_xor(s, off);
    float inv = 1.0f / s;
    p[lane] = v0 * inv; p[lane + 64] = v1 * inv; p[lane + 128] = v2 * inv; p[lane + 192] = v3 * inv;
}

// ---------------- pooling ----------------
__global__ void cnt_kernel(const int* __restrict__ batch, float* __restrict__ cnt, int N) {
    int i = blockIdx.x * blockDim.x + threadIdx.x;
    if (i < N) atomicAdd(&cnt[batch[i]], 1.0f);
}

__global__ void pool_kernel(const float* __restrict__ attn, const float* __restrict__ x3,
                            const int* __restrict__ batch, float* __restrict__ sums, long long total) {
    long long idx = (long long)blockIdx.x * blockDim.x + threadIdx.x;
    if (idx >= total) return;
    int n = (int)(idx >> 8);
    int j = (int)(idx & 255);
    atomicAdd(&sums[((size_t)batch[n] << 8) + j], attn[idx] * x3[idx]);
}

// ---------------- final: out[b] = dot(pooled + fp + fg, Wfc) + bfc ----------------
__global__ void final_kernel(const float* __restrict__ sums, const float* __restrict__ cnt,
                             const float* __restrict__ fp, const float* __restrict__ fg,
                             const float* __restrict__ Wfc, const float* __restrict__ bfc,
                             float* __restrict__ out, int B) {
    int b = blockIdx.x * 4 + (threadIdx.x >> 6);
    int lane = threadIdx.x & 63;
    if (b >= B) return;
    float inv = 1.0f / fmaxf(cnt[b], 1.0f);
    float acc = 0.0f;
    #pragma unroll
    for (int i = 0; i < 4; ++i) {
        int j = lane + i * 64;
        size_t off = (size_t)b * 256 + j;
        acc += (sums[off] * inv + fp[off] + fg[off]) * Wfc[j];
    }
    for (int off = 32; off; off >>= 1) acc += __shfl_xor(acc, off);
    if (lane == 0) out[b] = acc + bfc[0];
}

extern "C" void kernel_launch(void* const* d_in, const int* in_sizes, int n_in,
                              void* d_out, int out_size, void* d_ws, size_t ws_size,
                              hipStream_t stream) {
    const float* x     = (const float*)d_in[0];
    const int*   ei    = (const int*)d_in[1];
    const int*   batch = (const int*)d_in[2];
    const float* fpin  = (const float*)d_in[3];
    const float* fgin  = (const float*)d_in[4];
    const float* W1  = (const float*)d_in[5];  const float* b1  = (const float*)d_in[6];
    const float* W2  = (const float*)d_in[7];  const float* b2  = (const float*)d_in[8];
    const float* W3  = (const float*)d_in[9];  const float* b3  = (const float*)d_in[10];
    const float* Wr1 = (const float*)d_in[11]; const float* br1 = (const float*)d_in[12];
    const float* Wr2 = (const float*)d_in[13]; const float* br2 = (const float*)d_in[14];
    const float* Wfp = (const float*)d_in[15]; const float* bfp = (const float*)d_in[16];
    const float* Wfg = (const float*)d_in[17]; const float* bfg = (const float*)d_in[18];
    const float* attnW = (const float*)d_in[19];
    const float* Wfc = (const float*)d_in[20]; const float* bfc = (const float*)d_in[21];
    float* out = (float*)d_out;

    const int N = in_sizes[0] / 64;
    const int E = in_sizes[1] / 2;
    const int B = in_sizes[3] / 2048;
    const int* src = ei;
    const int* dst = ei + E;

    float* w = (float*)d_ws;
    size_t o = 0;
    float* dinv = w + o; o += (size_t)((N + 255) & ~255);
    const size_t NB = (size_t)N * 256;
    float* Q  = w + o; o += NB;   // h1 | x1, later agg3/x3
    float* R0 = w + o; o += NB;   // h2 / h3 / attn
    float* R1 = w + o; o += NB;   // r2 / r3
    float* R2 = w + o; o += NB;   // agg2 -> x2
    float* fp = w + o; o += (size_t)B * 256;
    float* fg = w + o; o += (size_t)B * 256;
    float* sums = w + o; o += (size_t)B * 256;
    float* cnt  = w + o; o += (size_t)B;
    (void)ws_size; (void)n_in; (void)out_size;

    float* h1 = Q;
    float* x1 = Q + (size_t)N * 128;

    dim3 blk(16, 16);

    hipMemsetAsync(dinv, 0, (size_t)N * sizeof(float), stream);
    hipMemsetAsync(sums, 0, (size_t)B * 256 * sizeof(float), stream);
    hipMemsetAsync(cnt,  0, (size_t)B * sizeof(float), stream);

    deg_count_kernel<<<CDIV(E, 256), 256, 0, stream>>>(dst, dinv, E);
    dinv_kernel<<<CDIV(N, 256), 256, 0, stream>>>(dinv, N);

    // ---- layer 1: x1 = relu(gcn(x, W1, b1)) ----
    gemm_kernel<<<dim3(CDIV(N, 64), 2), blk, 0, stream>>>(x, W1, nullptr, h1, N, 64, 128, 0);
    long long t1 = (long long)N * 128;
    long long te1 = (long long)E * 128;
    self_init_kernel<7><<<CDIV(t1, 256), 256, 0, stream>>>(h1, dinv, x1, t1);
    edge_scatter_kernel<7><<<CDIV(te1, 256), 256, 0, stream>>>(h1, x1, src, dst, dinv, te1);
    bias_res_relu_kernel<7><<<CDIV(t1, 256), 256, 0, stream>>>(x1, b1, nullptr, t1);

    // ---- layer 2: x2 = relu(gcn(x1, W2, b2) + x1@Wr1 + br1) ----
    long long t2 = (long long)N * 256;
    long long te2 = (long long)E * 256;
    gemm_kernel<<<dim3(CDIV(N, 64), 4), blk, 0, stream>>>(x1, W2, nullptr, R0, N, 128, 256, 0);
    gemm_kernel<<<dim3(CDIV(N, 64), 4), blk, 0, stream>>>(x1, Wr1, br1, R1, N, 128, 256, 0);
    self_init_kernel<8><<<CDIV(t2, 256), 256, 0, stream>>>(R0, dinv, R2, t2);
    edge_scatter_kernel<8><<<CDIV(te2, 256), 256, 0, stream>>>(R0, R2, src, dst, dinv, te2);
    bias_res_relu_kernel<8><<<CDIV(t2, 256), 256, 0, stream>>>(R2, b2, R1, t2);
    float* x2 = R2;

    // ---- layer 3: x3 = relu(gcn(x2, W3, b3) + x2@Wr2 + br2) ----
    gemm_kernel<<<dim3(CDIV(N, 64), 4), blk, 0, stream>>>(x2, W3, nullptr, R0, N, 256, 256, 0);
    gemm_kernel<<<dim3(CDIV(N, 64), 4), blk, 0, stream>>>(x2, Wr2, br2, R1, N, 256, 256, 0);
    self_init_kernel<8><<<CDIV(t2, 256), 256, 0, stream>>>(R0, dinv, Q, t2);
    edge_scatter_kernel<8><<<CDIV(te2, 256), 256, 0, stream>>>(R0, Q, src, dst, dinv, te2);
    bias_res_relu_kernel<8><<<CDIV(t2, 256), 256, 0, stream>>>(Q, b3, R1, t2);
    float* x3 = Q;

    // ---- attention: attn = softmax(x3 @ attn_W) ----
    gemm_kernel<<<dim3(CDIV(N, 64), 4), blk, 0, stream>>>(x3, attnW, nullptr, R0, N, 256, 256, 0);
    softmax256_kernel<<<CDIV(N, 4), 256, 0, stream>>>(R0, N);

    // ---- fp / fg MLPs ----
    gemm_kernel<<<dim3(CDIV(B, 64), 4), blk, 0, stream>>>(fpin, Wfp, bfp, fp, B, 2048, 256, 1);
    gemm_kernel<<<dim3(CDIV(B, 64), 4), blk, 0, stream>>>(fgin, Wfg, bfg, fg, B, 167, 256, 1);

    // ---- pooling ----
    cnt_kernel<<<CDIV(N, 256), 256, 0, stream>>>(batch, cnt, N);
    pool_kernel<<<CDIV(t2, 256), 256, 0, stream>>>(R0, x3, batch, sums, t2);

    // ---- final ----
    final_kernel<<<CDIV(B, 4), 256, 0, stream>>>(sums, cnt, fp, fg, Wfc, bfc, out, B);
}

// Round 3
// 1169.167 us; speedup vs baseline: 2.8351x; 2.8351x over previous
//
#include <hip/hip_runtime.h>
#include <math.h>

#define CDIV(a,b) (((a)+(b)-1)/(b))

// ---------------- degree / dinv ----------------
__global__ void deg_count_kernel(const int* __restrict__ dst, int* __restrict__ deg, int E) {
    int e = blockIdx.x * blockDim.x + threadIdx.x;
    if (e < E) atomicAdd(&deg[dst[e]], 1);
}

__global__ void dinv_kernel(const int* __restrict__ deg, float* __restrict__ dinv, int N) {
    int i = blockIdx.x * blockDim.x + threadIdx.x;
    if (i < N) dinv[i] = rsqrtf((float)deg[i] + 1.0f);
}

// ---------------- single-block exclusive scan over deg -> off[0..N], off[N]=E ----------------
__global__ void scan_kernel(const int* __restrict__ deg, int* __restrict__ off, int N, int E) {
    __shared__ int wsum[16];
    __shared__ int carry_s;
    const int t = threadIdx.x;          // 0..1023
    const int lane = t & 63, wid = t >> 6;
    if (t == 0) carry_s = 0;
    __syncthreads();
    for (int base = 0; base < N; base += 1024) {
        int i = base + t;
        int v = (i < N) ? deg[i] : 0;
        int x = v;
        #pragma unroll
        for (int ofs = 1; ofs < 64; ofs <<= 1) {
            int y = __shfl_up(x, ofs, 64);
            if (lane >= ofs) x += y;
        }
        if (lane == 63) wsum[wid] = x;
        __syncthreads();
        if (wid == 0) {
            int wv = (lane < 16) ? wsum[lane] : 0;
            #pragma unroll
            for (int ofs = 1; ofs < 16; ofs <<= 1) {
                int y = __shfl_up(wv, ofs, 64);
                if (lane >= ofs) wv += y;
            }
            if (lane < 16) wsum[lane] = wv;    // inclusive wave prefix
        }
        __syncthreads();
        int carry = carry_s;
        int wexcl = (wid == 0) ? 0 : wsum[wid - 1];
        int incl = x + wexcl;
        if (i < N) off[i] = carry + incl - v;  // exclusive
        __syncthreads();
        if (t == 1023) carry_s = carry + incl;
        __syncthreads();
    }
    if (t == 0) off[N] = E;
}

// ---------------- CSR fill ----------------
__global__ void csr_fill_kernel(const int* __restrict__ src, const int* __restrict__ dst,
                                const int* __restrict__ off, int* __restrict__ pos,
                                const float* __restrict__ dinv,
                                int* __restrict__ csr_src, float* __restrict__ csr_nrm, int E) {
    int e = blockIdx.x * blockDim.x + threadIdx.x;
    if (e >= E) return;
    int s = src[e], d = dst[e];
    int p = off[d] + atomicAdd(&pos[d], 1);
    csr_src[p] = s;
    csr_nrm[p] = dinv[s] * dinv[d];
}

// ---------------- fused GCN aggregation (gather): agg = relu(sum + self + bias [+res]) ----------------
template<int F>
__global__ __launch_bounds__(F) void gcn_gather_kernel(
        const float* __restrict__ h, const float* __restrict__ dinv,
        const int* __restrict__ off, const int* __restrict__ csr_src,
        const float* __restrict__ csr_nrm, const float* __restrict__ bias,
        const float* __restrict__ res, float* __restrict__ outx) {
    const int n = blockIdx.x;
    const int j = threadIdx.x;
    float d = dinv[n];
    float acc = h[(size_t)n * F + j] * d * d;
    const int e1 = off[n + 1];
    int e = off[n];
    for (; e + 4 <= e1; e += 4) {
        int s0 = csr_src[e], s1 = csr_src[e + 1], s2 = csr_src[e + 2], s3 = csr_src[e + 3];
        float n0 = csr_nrm[e], n1 = csr_nrm[e + 1], n2 = csr_nrm[e + 2], n3 = csr_nrm[e + 3];
        float h0 = h[(size_t)s0 * F + j];
        float h1 = h[(size_t)s1 * F + j];
        float h2 = h[(size_t)s2 * F + j];
        float h3 = h[(size_t)s3 * F + j];
        acc += h0 * n0; acc += h1 * n1; acc += h2 * n2; acc += h3 * n3;
    }
    for (; e < e1; ++e) {
        int s0 = csr_src[e];
        acc += h[(size_t)s0 * F + j] * csr_nrm[e];
    }
    float v = acc + bias[j];
    if (res) v += res[(size_t)n * F + j];
    outx[(size_t)n * F + j] = fmaxf(v, 0.0f);
}

// ---------------- fp32 GEMM: C[M,N] = A[M,K] @ W[K,N]; 128x128 tile, 8x8/thread ----------------
template<bool SPLITK>
__global__ __launch_bounds__(256) void gemm_kernel(
        const float* __restrict__ A, const float* __restrict__ W,
        const float* __restrict__ bias, float* __restrict__ C,
        int M, int K, int N, int do_relu, int kchunk) {
    __shared__ float As[16][128];   // [k][row]
    __shared__ float Ws[16][128];   // [k][col]
    const int tid = threadIdx.x;
    const int tx = tid & 15;
    const int ty = tid >> 4;
    const int row0 = blockIdx.x * 128;
    const int col0 = blockIdx.y * 128;
    int kbeg = 0, kend = K;
    if (SPLITK) { kbeg = blockIdx.z * kchunk; kend = min(K, kbeg + kchunk); }
    float acc[8][8] = {};
    for (int k0 = kbeg; k0 < kend; k0 += 16) {
        #pragma unroll
        for (int i = 0; i < 2; ++i) {
            int s = tid * 2 + i;
            int r = s >> 2, c = (s & 3) << 2;
            int gr = row0 + r;
            float4 v = make_float4(0.f, 0.f, 0.f, 0.f);
            if (gr < M) {
                if (k0 + c + 3 < kend) {
                    v = *(const float4*)(A + (size_t)gr * K + k0 + c);
                } else {
                    float t0 = (k0 + c     < kend) ? A[(size_t)gr * K + k0 + c    ] : 0.f;
                    float t1 = (k0 + c + 1 < kend) ? A[(size_t)gr * K + k0 + c + 1] : 0.f;
                    float t2 = (k0 + c + 2 < kend) ? A[(size_t)gr * K + k0 + c + 2] : 0.f;
                    float t3 = (k0 + c + 3 < kend) ? A[(size_t)gr * K + k0 + c + 3] : 0.f;
                    v = make_float4(t0, t1, t2, t3);
                }
            }
            As[c + 0][r] = v.x; As[c + 1][r] = v.y; As[c + 2][r] = v.z; As[c + 3][r] = v.w;
        }
        #pragma unroll
        for (int i = 0; i < 2; ++i) {
            int s = tid * 2 + i;
            int kk = s >> 5, c = (s & 31) << 2;
            int gk = k0 + kk, gc = col0 + c;
            float4 v = make_float4(0.f, 0.f, 0.f, 0.f);
            if (gk < kend) {
                if (gc + 3 < N) {
                    v = *(const float4*)(W + (size_t)gk * N + gc);
                } else {
                    float t0 = (gc     < N) ? W[(size_t)gk * N + gc    ] : 0.f;
                    float t1 = (gc + 1 < N) ? W[(size_t)gk * N + gc + 1] : 0.f;
                    float t2 = (gc + 2 < N) ? W[(size_t)gk * N + gc + 2] : 0.f;
                    float t3 = (gc + 3 < N) ? W[(size_t)gk * N + gc + 3] : 0.f;
                    v = make_float4(t0, t1, t2, t3);
                }
            }
            *(float4*)&Ws[kk][c] = v;
        }
        __syncthreads();
        #pragma unroll
        for (int kk = 0; kk < 16; ++kk) {
            float a[8], b[8];
            *(float4*)&a[0] = *(const float4*)&As[kk][ty * 4];
            *(float4*)&a[4] = *(const float4*)&As[kk][ty * 4 + 64];
            *(float4*)&b[0] = *(const float4*)&Ws[kk][tx * 4];
            *(float4*)&b[4] = *(const float4*)&Ws[kk][tx * 4 + 64];
            #pragma unroll
            for (int i2 = 0; i2 < 8; ++i2)
                #pragma unroll
                for (int j2 = 0; j2 < 8; ++j2)
                    acc[i2][j2] += a[i2] * b[j2];
        }
        __syncthreads();
    }
    #pragma unroll
    for (int rh = 0; rh < 2; ++rh) {
        #pragma unroll
        for (int ii = 0; ii < 4; ++ii) {
            int gr = row0 + ty * 4 + rh * 64 + ii;
            if (gr >= M) continue;
            #pragma unroll
            for (int ch = 0; ch < 2; ++ch) {
                int gc = col0 + tx * 4 + ch * 64;
                float v[4];
                #pragma unroll
                for (int q = 0; q < 4; ++q) v[q] = acc[rh * 4 + ii][ch * 4 + q];
                if (SPLITK) {
                    #pragma unroll
                    for (int q = 0; q < 4; ++q)
                        if (gc + q < N) atomicAdd(&C[(size_t)gr * N + gc + q], v[q]);
                } else {
                    if (bias) {
                        #pragma unroll
                        for (int q = 0; q < 4; ++q) v[q] += bias[gc + q];
                    }
                    if (do_relu) {
                        #pragma unroll
                        for (int q = 0; q < 4; ++q) v[q] = fmaxf(v[q], 0.f);
                    }
                    if (gc + 3 < N) {
                        *(float4*)(C + (size_t)gr * N + gc) = make_float4(v[0], v[1], v[2], v[3]);
                    } else {
                        #pragma unroll
                        for (int q = 0; q < 4; ++q)
                            if (gc + q < N) C[(size_t)gr * N + gc + q] = v[q];
                    }
                }
            }
        }
    }
}

// ---------------- bias+relu epilogue (for split-K output) ----------------
__global__ void bias_relu_kernel(float* __restrict__ X, const float* __restrict__ bias, long long total) {
    long long idx = (long long)blockIdx.x * blockDim.x + threadIdx.x;
    if (idx >= total) return;
    int j = (int)(idx & 255);
    X[idx] = fmaxf(X[idx] + bias[j], 0.0f);
}

// ---------------- softmax over 256 cols, one wave per row ----------------
__global__ void softmax256_kernel(float* __restrict__ X, int M) {
    int row = blockIdx.x * 4 + (threadIdx.x >> 6);
    int lane = threadIdx.x & 63;
    if (row >= M) return;
    float* p = X + (size_t)row * 256;
    float v0 = p[lane], v1 = p[lane + 64], v2 = p[lane + 128], v3 = p[lane + 192];
    float m = fmaxf(fmaxf(v0, v1), fmaxf(v2, v3));
    for (int off = 32; off; off >>= 1) m = fmaxf(m, __shfl_xor(m, off));
    v0 = expf(v0 - m); v1 = expf(v1 - m); v2 = expf(v2 - m); v3 = expf(v3 - m);
    float s = v0 + v1 + v2 + v3;
    for (int off = 32; off; off >>= 1) s += __shfl_xor(s, off);
    float inv = 1.0f / s;
    p[lane] = v0 * inv; p[lane + 64] = v1 * inv; p[lane + 128] = v2 * inv; p[lane + 192] = v3 * inv;
}

// ---------------- pooling: one block per graph (batch sorted) ----------------
__global__ __launch_bounds__(256) void pool_kernel(
        const float* __restrict__ attn, const float* __restrict__ x3,
        const int* __restrict__ batch, float* __restrict__ pooled, int N, int B) {
    const int b = blockIdx.x;
    const int j = threadIdx.x;   // 256
    int lo = 0, hi = N;
    while (lo < hi) { int m = (lo + hi) >> 1; if (batch[m] < b) lo = m + 1; else hi = m; }
    int s0 = lo;
    hi = N;
    while (lo < hi) { int m = (lo + hi) >> 1; if (batch[m] <= b) lo = m + 1; else hi = m; }
    int s1 = lo;
    float acc = 0.f;
    for (int n = s0; n < s1; ++n)
        acc += attn[(size_t)n * 256 + j] * x3[(size_t)n * 256 + j];
    float inv = 1.0f / fmaxf((float)(s1 - s0), 1.0f);
    pooled[(size_t)b * 256 + j] = acc * inv;
}

// ---------------- final: out[b] = dot(pooled + fp + fg, Wfc) + bfc ----------------
__global__ void final_kernel(const float* __restrict__ pooled, const float* __restrict__ fp,
                             const float* __restrict__ fg, const float* __restrict__ Wfc,
                             const float* __restrict__ bfc, float* __restrict__ out, int B) {
    int b = blockIdx.x * 4 + (threadIdx.x >> 6);
    int lane = threadIdx.x & 63;
    if (b >= B) return;
    float acc = 0.0f;
    #pragma unroll
    for (int i = 0; i < 4; ++i) {
        int j = lane + i * 64;
        size_t o = (size_t)b * 256 + j;
        acc += (pooled[o] + fp[o] + fg[o]) * Wfc[j];
    }
    for (int off = 32; off; off >>= 1) acc += __shfl_xor(acc, off);
    if (lane == 0) out[b] = acc + bfc[0];
}

extern "C" void kernel_launch(void* const* d_in, const int* in_sizes, int n_in,
                              void* d_out, int out_size, void* d_ws, size_t ws_size,
                              hipStream_t stream) {
    const float* x     = (const float*)d_in[0];
    const int*   ei    = (const int*)d_in[1];
    const int*   batch = (const int*)d_in[2];
    const float* fpin  = (const float*)d_in[3];
    const float* fgin  = (const float*)d_in[4];
    const float* W1  = (const float*)d_in[5];  const float* b1  = (const float*)d_in[6];
    const float* W2  = (const float*)d_in[7];  const float* b2  = (const float*)d_in[8];
    const float* W3  = (const float*)d_in[9];  const float* b3  = (const float*)d_in[10];
    const float* Wr1 = (const float*)d_in[11]; const float* br1 = (const float*)d_in[12];
    const float* Wr2 = (const float*)d_in[13]; const float* br2 = (const float*)d_in[14];
    const float* Wfp = (const float*)d_in[15]; const float* bfp = (const float*)d_in[16];
    const float* Wfg = (const float*)d_in[17]; const float* bfg = (const float*)d_in[18];
    const float* attnW = (const float*)d_in[19];
    const float* Wfc = (const float*)d_in[20]; const float* bfc = (const float*)d_in[21];
    float* out = (float*)d_out;

    const int N = in_sizes[0] / 64;
    const int E = in_sizes[1] / 2;
    const int B = in_sizes[3] / 2048;
    const int* src = ei;
    const int* dst = ei + E;

    float* w = (float*)d_ws;
    size_t o = 0;
    const size_t Na = (size_t)((N + 255) & ~255);
    float* dinv    = w + o; o += Na;
    int*   deg_i   = (int*)(w + o); o += Na;
    int*   pos     = (int*)(w + o); o += Na;
    int*   off     = (int*)(w + o); o += Na + 256;
    int*   csr_src = (int*)(w + o); o += (size_t)((E + 255) & ~255);
    float* csr_nrm = w + o; o += (size_t)((E + 255) & ~255);
    const size_t NB = (size_t)N * 256;
    float* Q  = w + o; o += NB;
    float* R0 = w + o; o += NB;
    float* R1 = w + o; o += NB;
    float* R2 = w + o; o += NB;
    float* fp = w + o; o += (size_t)B * 256;
    float* fg = w + o; o += (size_t)B * 256;
    float* pooled = w + o; o += (size_t)B * 256;
    (void)ws_size; (void)n_in; (void)out_size;

    float* h1 = Q;
    float* x1 = Q + (size_t)N * 128;

    // ---- CSR build ----
    hipMemsetAsync(deg_i, 0, (size_t)N * sizeof(int), stream);
    hipMemsetAsync(pos,   0, (size_t)N * sizeof(int), stream);
    hipMemsetAsync(fp,    0, (size_t)B * 256 * sizeof(float), stream);
    deg_count_kernel<<<CDIV(E, 256), 256, 0, stream>>>(dst, deg_i, E);
    dinv_kernel<<<CDIV(N, 256), 256, 0, stream>>>(deg_i, dinv, N);
    scan_kernel<<<1, 1024, 0, stream>>>(deg_i, off, N, E);
    csr_fill_kernel<<<CDIV(E, 256), 256, 0, stream>>>(src, dst, off, pos, dinv, csr_src, csr_nrm, E);

    // ---- layer 1: x1 = relu(gcn(x, W1, b1)) ----
    gemm_kernel<false><<<dim3(CDIV(N, 128), 1), 256, 0, stream>>>(x, W1, nullptr, h1, N, 64, 128, 0, 0);
    gcn_gather_kernel<128><<<N, 128, 0, stream>>>(h1, dinv, off, csr_src, csr_nrm, b1, nullptr, x1);

    // ---- layer 2: x2 = relu(gcn(x1, W2, b2) + x1@Wr1 + br1) ----
    gemm_kernel<false><<<dim3(CDIV(N, 128), 2), 256, 0, stream>>>(x1, W2, nullptr, R0, N, 128, 256, 0, 0);
    gemm_kernel<false><<<dim3(CDIV(N, 128), 2), 256, 0, stream>>>(x1, Wr1, br1, R1, N, 128, 256, 0, 0);
    gcn_gather_kernel<256><<<N, 256, 0, stream>>>(R0, dinv, off, csr_src, csr_nrm, b2, R1, R2);
    float* x2 = R2;

    // ---- layer 3: x3 = relu(gcn(x2, W3, b3) + x2@Wr2 + br2) ----
    gemm_kernel<false><<<dim3(CDIV(N, 128), 2), 256, 0, stream>>>(x2, W3, nullptr, R0, N, 256, 256, 0, 0);
    gemm_kernel<false><<<dim3(CDIV(N, 128), 2), 256, 0, stream>>>(x2, Wr2, br2, R1, N, 256, 256, 0, 0);
    gcn_gather_kernel<256><<<N, 256, 0, stream>>>(R0, dinv, off, csr_src, csr_nrm, b3, R1, Q);
    float* x3 = Q;

    // ---- attention ----
    gemm_kernel<false><<<dim3(CDIV(N, 128), 2), 256, 0, stream>>>(x3, attnW, nullptr, R0, N, 256, 256, 0, 0);
    softmax256_kernel<<<CDIV(N, 4), 256, 0, stream>>>(R0, N);

    // ---- fp / fg MLPs ----
    gemm_kernel<true><<<dim3(CDIV(B, 128), 2, 8), 256, 0, stream>>>(fpin, Wfp, nullptr, fp, B, 2048, 256, 0, 256);
    bias_relu_kernel<<<CDIV((long long)B * 256, 256), 256, 0, stream>>>(fp, bfp, (long long)B * 256);
    gemm_kernel<false><<<dim3(CDIV(B, 128), 2), 256, 0, stream>>>(fgin, Wfg, bfg, fg, B, 167, 256, 1, 0);

    // ---- pooling (batch sorted -> per-graph segments) ----
    pool_kernel<<<B, 256, 0, stream>>>(R0, x3, batch, pooled, N, B);

    // ---- final ----
    final_kernel<<<CDIV(B, 4), 256, 0, stream>>>(pooled, fp, fg, Wfc, bfc, out, B);
}

// Round 5
// 921.122 us; speedup vs baseline: 3.5986x; 1.2693x over previous
//
#include <hip/hip_runtime.h>
#include <math.h>

#define CDIV(a,b) (((a)+(b)-1)/(b))

typedef __attribute__((ext_vector_type(8))) short bf16x8;
typedef __attribute__((ext_vector_type(4))) float f32x4;

__device__ inline unsigned short f2bf(float f) {           // RNE bf16
    unsigned int u = __float_as_uint(f);
    u += 0x7fffu + ((u >> 16) & 1u);
    return (unsigned short)(u >> 16);
}
__device__ inline float bf2f(unsigned short h) { return __uint_as_float(((unsigned int)h) << 16); }

// ---------------- degree / dinv ----------------
__global__ void deg_count_kernel(const int* __restrict__ dst, int* __restrict__ deg, int E) {
    int e = blockIdx.x * blockDim.x + threadIdx.x;
    if (e < E) atomicAdd(&deg[dst[e]], 1);
}

__global__ void dinv_kernel(const int* __restrict__ deg, float* __restrict__ dinv, int N) {
    int i = blockIdx.x * blockDim.x + threadIdx.x;
    if (i < N) dinv[i] = rsqrtf((float)deg[i] + 1.0f);
}

// ---------------- single-block exclusive scan over deg -> off[0..N], off[N]=E ----------------
__global__ void scan_kernel(const int* __restrict__ deg, int* __restrict__ off, int N, int E) {
    __shared__ int wsum[16];
    __shared__ int carry_s;
    const int t = threadIdx.x;          // 0..1023
    const int lane = t & 63, wid = t >> 6;
    if (t == 0) carry_s = 0;
    __syncthreads();
    for (int base = 0; base < N; base += 1024) {
        int i = base + t;
        int v = (i < N) ? deg[i] : 0;
        int x = v;
        #pragma unroll
        for (int ofs = 1; ofs < 64; ofs <<= 1) {
            int y = __shfl_up(x, ofs, 64);
            if (lane >= ofs) x += y;
        }
        if (lane == 63) wsum[wid] = x;
        __syncthreads();
        if (wid == 0) {
            int wv = (lane < 16) ? wsum[lane] : 0;
            #pragma unroll
            for (int ofs = 1; ofs < 16; ofs <<= 1) {
                int y = __shfl_up(wv, ofs, 64);
                if (lane >= ofs) wv += y;
            }
            if (lane < 16) wsum[lane] = wv;
        }
        __syncthreads();
        int carry = carry_s;
        int wexcl = (wid == 0) ? 0 : wsum[wid - 1];
        int incl = x + wexcl;
        if (i < N) off[i] = carry + incl - v;
        __syncthreads();
        if (t == 1023) carry_s = carry + incl;
        __syncthreads();
    }
    if (t == 0) off[N] = E;
}

// ---------------- CSR fill ----------------
__global__ void csr_fill_kernel(const int* __restrict__ src, const int* __restrict__ dst,
                                const int* __restrict__ off, int* __restrict__ pos,
                                int* __restrict__ csr_src, int E) {
    int e = blockIdx.x * blockDim.x + threadIdx.x;
    if (e >= E) return;
    int s = src[e], d = dst[e];
    int p = off[d] + atomicAdd(&pos[d], 1);
    csr_src[p] = s;
}

// ---------------- split fp32 -> (hi,lo) bf16 ----------------
__global__ void split_kernel(const float* __restrict__ src, unsigned short* __restrict__ hi,
                             unsigned short* __restrict__ lo, long long total,
                             int C, int ldd, int coff) {
    long long idx = (long long)blockIdx.x * blockDim.x + threadIdx.x;
    if (idx >= total) return;
    int r = (int)(idx / C);
    int c = (int)(idx - (long long)r * C);
    float v = src[idx];
    unsigned short h = f2bf(v);
    size_t o = (size_t)r * ldd + coff + c;
    hi[o] = h;
    lo[o] = f2bf(v - bf2f(h));
}

__global__ void bcat_kernel(const float* __restrict__ b, float* __restrict__ bcat) {
    int j = blockIdx.x * blockDim.x + threadIdx.x;
    if (j < 512) bcat[j] = (j < 256) ? 0.f : b[j - 256];
}

// ---------------- fused GCN aggregation (gather), nrm computed inline ----------------
template<int F>
__global__ __launch_bounds__(F) void gcn_gather_kernel(
        const float* __restrict__ h, int ldh, const float* __restrict__ dinv,
        const int* __restrict__ off, const int* __restrict__ csr_src,
        const float* __restrict__ bias, const float* __restrict__ res, int ldr,
        unsigned short* __restrict__ outhi, unsigned short* __restrict__ outlo) {
    const int n = blockIdx.x;
    const int j = threadIdx.x;
    float dd = dinv[n];
    float acc = h[(size_t)n * ldh + j] * dd * dd;
    const int e1 = off[n + 1];
    int e = off[n];
    for (; e + 4 <= e1; e += 4) {
        int s0 = csr_src[e], s1 = csr_src[e + 1], s2 = csr_src[e + 2], s3 = csr_src[e + 3];
        float n0 = dinv[s0] * dd, n1 = dinv[s1] * dd, n2 = dinv[s2] * dd, n3 = dinv[s3] * dd;
        float h0 = h[(size_t)s0 * ldh + j];
        float h1 = h[(size_t)s1 * ldh + j];
        float h2 = h[(size_t)s2 * ldh + j];
        float h3 = h[(size_t)s3 * ldh + j];
        acc += h0 * n0; acc += h1 * n1; acc += h2 * n2; acc += h3 * n3;
    }
    for (; e < e1; ++e) {
        int s0 = csr_src[e];
        acc += h[(size_t)s0 * ldh + j] * (dinv[s0] * dd);
    }
    float v = acc + bias[j];
    if (res) v += res[(size_t)n * ldr + j];
    v = fmaxf(v, 0.0f);
    unsigned short hv = f2bf(v);
    outhi[(size_t)n * F + j] = hv;
    outlo[(size_t)n * F + j] = f2bf(v - bf2f(hv));
}

// ---------------- split-bf16 MFMA GEMM: C = A@W (+bias) ----------------
// A: [M][K] hi/lo bf16; W: [K][NW] hi/lo bf16; C: [M][NW] fp32 (+ z partials)
// tile 128x128, 4 waves (2x2), each wave 64x64 via 4x4 mfma_16x16x32, 3-term split.
__global__ __launch_bounds__(256) void mfma_gemm_kernel(
        const unsigned short* __restrict__ Ahi, const unsigned short* __restrict__ Alo,
        const unsigned short* __restrict__ Whi, const unsigned short* __restrict__ Wlo,
        const float* __restrict__ bias, float* __restrict__ C,
        int M, int K, int NW, int kchunk) {
    __shared__ unsigned short AsH[128 * 40];
    __shared__ unsigned short AsL[128 * 40];
    __shared__ unsigned short WsH[128 * 40];
    __shared__ unsigned short WsL[128 * 40];
    const int tid = threadIdx.x;
    const int row0 = blockIdx.x * 128;
    const int col0 = blockIdx.y * 128;
    int kbeg = 0, kend = K;
    size_t zoff = 0;
    if (kchunk) {
        kbeg = blockIdx.z * kchunk;
        kend = kbeg + kchunk;
        zoff = (size_t)blockIdx.z * M * NW;
    }
    const int w = tid >> 6, l = tid & 63;
    const int wm = w >> 1, wn = w & 1;
    const int lrow = l & 15, lk = l >> 4;
    f32x4 acc[4][4] = {};
    for (int k0 = kbeg; k0 < kend; k0 += 32) {
        #pragma unroll
        for (int i = 0; i < 2; ++i) {
            int c = tid * 2 + i;              // 0..511
            int r = c >> 2, kq = c & 3;
            int gr = row0 + r;
            uint4 vh = make_uint4(0, 0, 0, 0), vl = make_uint4(0, 0, 0, 0);
            if (gr < M) {
                size_t g = (size_t)gr * K + k0 + kq * 8;
                vh = *(const uint4*)&Ahi[g];
                vl = *(const uint4*)&Alo[g];
            }
            *(uint4*)&AsH[r * 40 + kq * 8] = vh;
            *(uint4*)&AsL[r * 40 + kq * 8] = vl;
        }
        #pragma unroll
        for (int i = 0; i < 2; ++i) {
            int c = tid + i * 256;            // 0..511
            int col = c & 127, kq = c >> 7;
            int gc = col0 + col;
            bf16x8 th, tl;
            #pragma unroll
            for (int q = 0; q < 8; ++q) {
                size_t g = (size_t)(k0 + kq * 8 + q) * NW + gc;
                th[q] = (short)Whi[g];
                tl[q] = (short)Wlo[g];
            }
            *(bf16x8*)&WsH[col * 40 + kq * 8] = th;
            *(bf16x8*)&WsL[col * 40 + kq * 8] = tl;
        }
        __syncthreads();
        bf16x8 aH[4], aL[4], bH[4], bL[4];
        #pragma unroll
        for (int mi = 0; mi < 4; ++mi) {
            int r = wm * 64 + mi * 16 + lrow;
            aH[mi] = *(const bf16x8*)&AsH[r * 40 + lk * 8];
            aL[mi] = *(const bf16x8*)&AsL[r * 40 + lk * 8];
        }
        #pragma unroll
        for (int ni = 0; ni < 4; ++ni) {
            int cc = wn * 64 + ni * 16 + lrow;
            bH[ni] = *(const bf16x8*)&WsH[cc * 40 + lk * 8];
            bL[ni] = *(const bf16x8*)&WsL[cc * 40 + lk * 8];
        }
        #pragma unroll
        for (int mi = 0; mi < 4; ++mi)
            #pragma unroll
            for (int ni = 0; ni < 4; ++ni) {
                acc[mi][ni] = __builtin_amdgcn_mfma_f32_16x16x32_bf16(aH[mi], bH[ni], acc[mi][ni], 0, 0, 0);
                acc[mi][ni] = __builtin_amdgcn_mfma_f32_16x16x32_bf16(aH[mi], bL[ni], acc[mi][ni], 0, 0, 0);
                acc[mi][ni] = __builtin_amdgcn_mfma_f32_16x16x32_bf16(aL[mi], bH[ni], acc[mi][ni], 0, 0, 0);
            }
        __syncthreads();
    }
    #pragma unroll
    for (int mi = 0; mi < 4; ++mi) {
        #pragma unroll
        for (int ni = 0; ni < 4; ++ni) {
            int gc = col0 + wn * 64 + ni * 16 + lrow;
            float bb = bias ? bias[gc] : 0.f;
            #pragma unroll
            for (int q = 0; q < 4; ++q) {
                int gr = row0 + wm * 64 + mi * 16 + lk * 4 + q;
                if (gr < M)
                    C[zoff + (size_t)gr * NW + gc] = acc[mi][ni][q] + bb;
            }
        }
    }
}

// ---------------- reduce split-K partials + bias + relu ----------------
__global__ void reduce_fp_kernel(const float* __restrict__ part, const float* __restrict__ bias,
                                 float* __restrict__ outp, int total, int stride, int nz) {
    int idx = blockIdx.x * blockDim.x + threadIdx.x;
    if (idx >= total) return;
    float s = 0.f;
    for (int z = 0; z < nz; ++z) s += part[(size_t)z * stride + idx];
    outp[idx] = fmaxf(s + bias[idx & 255], 0.f);
}

// ---------------- fp32 GEMM (tiny fg matmul, K=167) ----------------
__global__ __launch_bounds__(256) void gemm_kernel(
        const float* __restrict__ A, const float* __restrict__ W,
        const float* __restrict__ bias, float* __restrict__ C,
        int M, int K, int N, int do_relu) {
    __shared__ float As[16][128];
    __shared__ float Ws[16][128];
    const int tid = threadIdx.x;
    const int tx = tid & 15;
    const int ty = tid >> 4;
    const int row0 = blockIdx.x * 128;
    const int col0 = blockIdx.y * 128;
    float acc[8][8] = {};
    for (int k0 = 0; k0 < K; k0 += 16) {
        #pragma unroll
        for (int i = 0; i < 2; ++i) {
            int s = tid * 2 + i;
            int r = s >> 2, c = (s & 3) << 2;
            int gr = row0 + r;
            float4 v = make_float4(0.f, 0.f, 0.f, 0.f);
            if (gr < M) {
                if (k0 + c + 3 < K) {
                    v = *(const float4*)(A + (size_t)gr * K + k0 + c);
                } else {
                    float t0 = (k0 + c     < K) ? A[(size_t)gr * K + k0 + c    ] : 0.f;
                    float t1 = (k0 + c + 1 < K) ? A[(size_t)gr * K + k0 + c + 1] : 0.f;
                    float t2 = (k0 + c + 2 < K) ? A[(size_t)gr * K + k0 + c + 2] : 0.f;
                    float t3 = (k0 + c + 3 < K) ? A[(size_t)gr * K + k0 + c + 3] : 0.f;
                    v = make_float4(t0, t1, t2, t3);
                }
            }
            As[c + 0][r] = v.x; As[c + 1][r] = v.y; As[c + 2][r] = v.z; As[c + 3][r] = v.w;
        }
        #pragma unroll
        for (int i = 0; i < 2; ++i) {
            int s = tid * 2 + i;
            int kk = s >> 5, c = (s & 31) << 2;
            int gk = k0 + kk, gc = col0 + c;
            float4 v = make_float4(0.f, 0.f, 0.f, 0.f);
            if (gk < K && gc + 3 < N) v = *(const float4*)(W + (size_t)gk * N + gc);
            *(float4*)&Ws[kk][c] = v;
        }
        __syncthreads();
        #pragma unroll
        for (int kk = 0; kk < 16; ++kk) {
            float a[8], b[8];
            *(float4*)&a[0] = *(const float4*)&As[kk][ty * 4];
            *(float4*)&a[4] = *(const float4*)&As[kk][ty * 4 + 64];
            *(float4*)&b[0] = *(const float4*)&Ws[kk][tx * 4];
            *(float4*)&b[4] = *(const float4*)&Ws[kk][tx * 4 + 64];
            #pragma unroll
            for (int i2 = 0; i2 < 8; ++i2)
                #pragma unroll
                for (int j2 = 0; j2 < 8; ++j2)
                    acc[i2][j2] += a[i2] * b[j2];
        }
        __syncthreads();
    }
    #pragma unroll
    for (int rh = 0; rh < 2; ++rh)
        #pragma unroll
        for (int ii = 0; ii < 4; ++ii) {
            int gr = row0 + ty * 4 + rh * 64 + ii;
            if (gr >= M) continue;
            #pragma unroll
            for (int ch = 0; ch < 2; ++ch) {
                int gc = col0 + tx * 4 + ch * 64;
                float v[4];
                #pragma unroll
                for (int q = 0; q < 4; ++q) {
                    v[q] = acc[rh * 4 + ii][ch * 4 + q] + (bias ? bias[gc + q] : 0.f);
                    if (do_relu) v[q] = fmaxf(v[q], 0.f);
                }
                if (gc + 3 < N)
                    *(float4*)(C + (size_t)gr * N + gc) = make_float4(v[0], v[1], v[2], v[3]);
            }
        }
}

// ---------------- softmax over 256 cols ----------------
__global__ void softmax256_kernel(float* __restrict__ X, int M) {
    int row = blockIdx.x * 4 + (threadIdx.x >> 6);
    int lane = threadIdx.x & 63;
    if (row >= M) return;
    float* p = X + (size_t)row * 256;
    float v0 = p[lane], v1 = p[lane + 64], v2 = p[lane + 128], v3 = p[lane + 192];
    float m = fmaxf(fmaxf(v0, v1), fmaxf(v2, v3));
    for (int off = 32; off; off >>= 1) m = fmaxf(m, __shfl_xor(m, off));
    v0 = expf(v0 - m); v1 = expf(v1 - m); v2 = expf(v2 - m); v3 = expf(v3 - m);
    float s = v0 + v1 + v2 + v3;
    for (int off = 32; off; off >>= 1) s += __shfl_xor(s, off);
    float inv = 1.0f / s;
    p[lane] = v0 * inv; p[lane + 64] = v1 * inv; p[lane + 128] = v2 * inv; p[lane + 192] = v3 * inv;
}

// ---------------- pooling: one block per graph (batch sorted); x3 = hi+lo ----------------
__global__ __launch_bounds__(256) void pool_kernel(
        const float* __restrict__ attn, const unsigned short* __restrict__ x3h,
        const unsigned short* __restrict__ x3l,
        const int* __restrict__ batch, float* __restrict__ pooled, int N, int B) {
    const int b = blockIdx.x;
    const int j = threadIdx.x;
    int lo = 0, hi = N;
    while (lo < hi) { int m = (lo + hi) >> 1; if (batch[m] < b) lo = m + 1; else hi = m; }
    int s0 = lo;
    hi = N;
    while (lo < hi) { int m = (lo + hi) >> 1; if (batch[m] <= b) lo = m + 1; else hi = m; }
    int s1 = lo;
    float acc = 0.f;
    for (int n = s0; n < s1; ++n) {
        size_t o = (size_t)n * 256 + j;
        acc += attn[o] * (bf2f(x3h[o]) + bf2f(x3l[o]));
    }
    float inv = 1.0f / fmaxf((float)(s1 - s0), 1.0f);
    pooled[(size_t)b * 256 + j] = acc * inv;
}

// ---------------- final ----------------
__global__ void final_kernel(const float* __restrict__ pooled, const float* __restrict__ fp,
                             const float* __restrict__ fg, const float* __restrict__ Wfc,
                             const float* __restrict__ bfc, float* __restrict__ out, int B) {
    int b = blockIdx.x * 4 + (threadIdx.x >> 6);
    int lane = threadIdx.x & 63;
    if (b >= B) return;
    float acc = 0.0f;
    #pragma unroll
    for (int i = 0; i < 4; ++i) {
        int j = lane + i * 64;
        size_t o = (size_t)b * 256 + j;
        acc += (pooled[o] + fp[o] + fg[o]) * Wfc[j];
    }
    for (int off = 32; off; off >>= 1) acc += __shfl_xor(acc, off);
    if (lane == 0) out[b] = acc + bfc[0];
}

extern "C" void kernel_launch(void* const* d_in, const int* in_sizes, int n_in,
                              void* d_out, int out_size, void* d_ws, size_t ws_size,
                              hipStream_t stream) {
    const float* x     = (const float*)d_in[0];
    const int*   ei    = (const int*)d_in[1];
    const int*   batch = (const int*)d_in[2];
    const float* fpin  = (const float*)d_in[3];
    const float* fgin  = (const float*)d_in[4];
    const float* W1  = (const float*)d_in[5];  const float* b1  = (const float*)d_in[6];
    const float* W2  = (const float*)d_in[7];  const float* b2  = (const float*)d_in[8];
    const float* W3  = (const float*)d_in[9];  const float* b3  = (const float*)d_in[10];
    const float* Wr1 = (const float*)d_in[11]; const float* br1 = (const float*)d_in[12];
    const float* Wr2 = (const float*)d_in[13]; const float* br2 = (const float*)d_in[14];
    const float* Wfp = (const float*)d_in[15]; const float* bfp = (const float*)d_in[16];
    const float* Wfg = (const float*)d_in[17]; const float* bfg = (const float*)d_in[18];
    const float* attnW = (const float*)d_in[19];
    const float* Wfc = (const float*)d_in[20]; const float* bfc = (const float*)d_in[21];
    float* out = (float*)d_out;

    const int Nn = in_sizes[0] / 64;
    const int E  = in_sizes[1] / 2;
    const int B  = in_sizes[3] / 2048;
    const int* src = ei;
    const int* dst = ei + E;

    char* wsb = (char*)d_ws;
    size_t woff = 0;
    auto alloc = [&](size_t bytes) -> void* {
        void* p = wsb + woff;
        woff += (bytes + 255) & ~(size_t)255;
        return p;
    };

    // ---- persistent ----
    int*   deg_i   = (int*)alloc((size_t)Nn * 4);
    int*   pos     = (int*)alloc((size_t)Nn * 4);
    int*   offv    = (int*)alloc(((size_t)Nn + 1) * 4);
    float* dinv    = (float*)alloc((size_t)Nn * 4);
    int*   csr_src = (int*)alloc((size_t)E * 4);
    float* CC      = (float*)alloc((size_t)Nn * 512 * 4);     // 102.4 MB
    char*  S1      = (char*)alloc((size_t)Nn * 1024);         // 51.2 MB (overlay slot 1)
    char*  S2      = (char*)alloc((size_t)Nn * 1024);         // 51.2 MB (overlay slot 2)
    unsigned short* W1h  = (unsigned short*)alloc(64 * 128 * 2);
    unsigned short* W1l  = (unsigned short*)alloc(64 * 128 * 2);
    unsigned short* Wc2h = (unsigned short*)alloc(128 * 512 * 2);
    unsigned short* Wc2l = (unsigned short*)alloc(128 * 512 * 2);
    unsigned short* Wc3h = (unsigned short*)alloc(256 * 512 * 2);
    unsigned short* Wc3l = (unsigned short*)alloc(256 * 512 * 2);
    unsigned short* aWh  = (unsigned short*)alloc(256 * 256 * 2);
    unsigned short* aWl  = (unsigned short*)alloc(256 * 256 * 2);
    float* bcat2  = (float*)alloc(512 * 4);
    float* bcat3  = (float*)alloc(512 * 4);
    (void)ws_size; (void)n_in; (void)out_size;

    // ---- S1 phase A: xin pair + x1 pair ----
    unsigned short* xinh = (unsigned short*)(S1);
    unsigned short* xinl = (unsigned short*)(S1 + (size_t)Nn * 128);
    unsigned short* x1h  = (unsigned short*)(S1 + (size_t)Nn * 256);
    unsigned short* x1l  = (unsigned short*)(S1 + (size_t)Nn * 512);
    // ---- S1 phase B: x3 pair (after x1/xin dead) ----
    unsigned short* x3h  = (unsigned short*)(S1);
    unsigned short* x3l  = (unsigned short*)(S1 + (size_t)Nn * 512);
    // ---- S2 phase A: x2 pair ----
    unsigned short* x2h  = (unsigned short*)(S2);
    unsigned short* x2l  = (unsigned short*)(S2 + (size_t)Nn * 512);
    // ---- S2 phase B: fp-MLP buffers (after x2 dead) ----
    unsigned short* fpinh = (unsigned short*)(S2);
    unsigned short* fpinl = (unsigned short*)(S2 + 4194304);
    unsigned short* Wfph  = (unsigned short*)(S2 + 8388608);
    unsigned short* Wfpl  = (unsigned short*)(S2 + 9437184);
    float* part   = (float*)(S2 + 10485760);
    float* fpb    = (float*)(S2 + 18874368);
    float* fgb    = (float*)(S2 + 19922944);
    float* pooled = (float*)(S2 + 20971520);

    // ---- CSR build ----
    hipMemsetAsync(deg_i, 0, (size_t)Nn * 4, stream);
    hipMemsetAsync(pos,   0, (size_t)Nn * 4, stream);
    deg_count_kernel<<<CDIV(E, 256), 256, 0, stream>>>(dst, deg_i, E);
    dinv_kernel<<<CDIV(Nn, 256), 256, 0, stream>>>(deg_i, dinv, Nn);
    scan_kernel<<<1, 1024, 0, stream>>>(deg_i, offv, Nn, E);
    csr_fill_kernel<<<CDIV(E, 256), 256, 0, stream>>>(src, dst, offv, pos, csr_src, E);

    // ---- weight/input splits (NOT fpin/Wfp yet — they live in S2 phase B) ----
    long long txin = (long long)Nn * 64;
    split_kernel<<<CDIV(txin, 256), 256, 0, stream>>>(x, xinh, xinl, txin, 64, 64, 0);
    split_kernel<<<CDIV(64 * 128, 256), 256, 0, stream>>>(W1, W1h, W1l, 64 * 128, 128, 128, 0);
    split_kernel<<<CDIV(128 * 256, 256), 256, 0, stream>>>(W2,  Wc2h, Wc2l, 128 * 256, 256, 512, 0);
    split_kernel<<<CDIV(128 * 256, 256), 256, 0, stream>>>(Wr1, Wc2h, Wc2l, 128 * 256, 256, 512, 256);
    split_kernel<<<CDIV(256 * 256, 256), 256, 0, stream>>>(W3,  Wc3h, Wc3l, 256 * 256, 256, 512, 0);
    split_kernel<<<CDIV(256 * 256, 256), 256, 0, stream>>>(Wr2, Wc3h, Wc3l, 256 * 256, 256, 512, 256);
    split_kernel<<<CDIV(256 * 256, 256), 256, 0, stream>>>(attnW, aWh, aWl, 256 * 256, 256, 256, 0);
    bcat_kernel<<<2, 256, 0, stream>>>(br1, bcat2);
    bcat_kernel<<<2, 256, 0, stream>>>(br2, bcat3);

    const int MB = CDIV(Nn, 128);

    // ---- layer 1 ----
    mfma_gemm_kernel<<<dim3(MB, 1), 256, 0, stream>>>(xinh, xinl, W1h, W1l, nullptr, CC, Nn, 64, 128, 0);
    gcn_gather_kernel<128><<<Nn, 128, 0, stream>>>(CC, 128, dinv, offv, csr_src,
                                                   b1, nullptr, 0, x1h, x1l);

    // ---- layer 2 (W2|Wr1 fused, N=512) ----
    mfma_gemm_kernel<<<dim3(MB, 4), 256, 0, stream>>>(x1h, x1l, Wc2h, Wc2l, bcat2, CC, Nn, 128, 512, 0);
    gcn_gather_kernel<256><<<Nn, 256, 0, stream>>>(CC, 512, dinv, offv, csr_src,
                                                   b2, CC + 256, 512, x2h, x2l);

    // ---- layer 3 (W3|Wr2 fused, N=512); after this x1/xin and then x2 are dead ----
    mfma_gemm_kernel<<<dim3(MB, 4), 256, 0, stream>>>(x2h, x2l, Wc3h, Wc3l, bcat3, CC, Nn, 256, 512, 0);
    gcn_gather_kernel<256><<<Nn, 256, 0, stream>>>(CC, 512, dinv, offv, csr_src,
                                                   b3, CC + 256, 512, x3h, x3l);

    // ---- attention logits ----
    mfma_gemm_kernel<<<dim3(MB, 2), 256, 0, stream>>>(x3h, x3l, aWh, aWl, nullptr, CC, Nn, 256, 256, 0);

    // ---- fp MLP (S2 phase B; x2 dead now) ----
    long long tfp = (long long)B * 2048;
    split_kernel<<<CDIV(tfp, 256), 256, 0, stream>>>(fpin, fpinh, fpinl, tfp, 2048, 2048, 0);
    split_kernel<<<CDIV(2048 * 256, 256), 256, 0, stream>>>(Wfp, Wfph, Wfpl, 2048 * 256, 256, 256, 0);
    mfma_gemm_kernel<<<dim3(CDIV(B, 128), 2, 8), 256, 0, stream>>>(fpinh, fpinl, Wfph, Wfpl, nullptr,
                                                                   part, B, 2048, 256, 256);
    reduce_fp_kernel<<<CDIV(B * 256, 256), 256, 0, stream>>>(part, bfp, fpb, B * 256, B * 256, 8);

    // ---- fg MLP (tiny, fp32 path) ----
    gemm_kernel<<<dim3(CDIV(B, 128), 2), 256, 0, stream>>>(fgin, Wfg, bfg, fgb, B, 167, 256, 1);

    // ---- softmax + pooling + final ----
    softmax256_kernel<<<CDIV(Nn, 4), 256, 0, stream>>>(CC, Nn);
    pool_kernel<<<B, 256, 0, stream>>>(CC, x3h, x3l, batch, pooled, Nn, B);
    final_kernel<<<CDIV(B, 4), 256, 0, stream>>>(pooled, fpb, fgb, Wfc, bfc, out, B);
}

// Round 6
// 838.229 us; speedup vs baseline: 3.9545x; 1.0989x over previous
//
#include <hip/hip_runtime.h>
#include <math.h>

#define CDIV(a,b) (((a)+(b)-1)/(b))

typedef __attribute__((ext_vector_type(8))) short bf16x8;
typedef __attribute__((ext_vector_type(4))) float f32x4;

__device__ inline unsigned short f2bf(float f) {           // RNE bf16
    unsigned int u = __float_as_uint(f);
    u += 0x7fffu + ((u >> 16) & 1u);
    return (unsigned short)(u >> 16);
}
__device__ inline float bf2f(unsigned short h) { return __uint_as_float(((unsigned int)h) << 16); }

// ---------------- degree / dinv ----------------
__global__ void deg_count_kernel(const int* __restrict__ dst, int* __restrict__ deg, int E) {
    int e = blockIdx.x * blockDim.x + threadIdx.x;
    if (e < E) atomicAdd(&deg[dst[e]], 1);
}

__global__ void dinv_kernel(const int* __restrict__ deg, float* __restrict__ dinv, int N) {
    int i = blockIdx.x * blockDim.x + threadIdx.x;
    if (i < N) dinv[i] = rsqrtf((float)deg[i] + 1.0f);
}

// ---------------- single-block exclusive scan over deg -> off[0..N], off[N]=E ----------------
__global__ void scan_kernel(const int* __restrict__ deg, int* __restrict__ off, int N, int E) {
    __shared__ int wsum[16];
    __shared__ int carry_s;
    const int t = threadIdx.x;          // 0..1023
    const int lane = t & 63, wid = t >> 6;
    if (t == 0) carry_s = 0;
    __syncthreads();
    for (int base = 0; base < N; base += 1024) {
        int i = base + t;
        int v = (i < N) ? deg[i] : 0;
        int x = v;
        #pragma unroll
        for (int ofs = 1; ofs < 64; ofs <<= 1) {
            int y = __shfl_up(x, ofs, 64);
            if (lane >= ofs) x += y;
        }
        if (lane == 63) wsum[wid] = x;
        __syncthreads();
        if (wid == 0) {
            int wv = (lane < 16) ? wsum[lane] : 0;
            #pragma unroll
            for (int ofs = 1; ofs < 16; ofs <<= 1) {
                int y = __shfl_up(wv, ofs, 64);
                if (lane >= ofs) wv += y;
            }
            if (lane < 16) wsum[lane] = wv;
        }
        __syncthreads();
        int carry = carry_s;
        int wexcl = (wid == 0) ? 0 : wsum[wid - 1];
        int incl = x + wexcl;
        if (i < N) off[i] = carry + incl - v;
        __syncthreads();
        if (t == 1023) carry_s = carry + incl;
        __syncthreads();
    }
    if (t == 0) off[N] = E;
}

// ---------------- CSR fill ----------------
__global__ void csr_fill_kernel(const int* __restrict__ src, const int* __restrict__ dst,
                                const int* __restrict__ off, int* __restrict__ pos,
                                int* __restrict__ csr_src, int E) {
    int e = blockIdx.x * blockDim.x + threadIdx.x;
    if (e >= E) return;
    int s = src[e], d = dst[e];
    int p = off[d] + atomicAdd(&pos[d], 1);
    csr_src[p] = s;
}

// ---------------- split fp32 -> (hi,lo) bf16 (row-major passthrough) ----------------
__global__ void split_kernel(const float* __restrict__ src, unsigned short* __restrict__ hi,
                             unsigned short* __restrict__ lo, long long total) {
    long long idx = (long long)blockIdx.x * blockDim.x + threadIdx.x;
    if (idx >= total) return;
    float v = src[idx];
    unsigned short h = f2bf(v);
    hi[idx] = h;
    lo[idx] = f2bf(v - bf2f(h));
}

// ---------------- transpose-split weights: src[K][N] -> dst[col][koff+k] (ldt) ----------------
__global__ void wsplit_t_kernel(const float* __restrict__ src, int K, int N,
                                unsigned short* __restrict__ dsth, unsigned short* __restrict__ dstl,
                                int ldt, int koff) {
    int idx = blockIdx.x * blockDim.x + threadIdx.x;
    if (idx >= K * N) return;
    int col = idx / K;
    int k = idx - col * K;
    float v = src[(size_t)k * N + col];
    unsigned short h = f2bf(v);
    size_t o = (size_t)col * ldt + koff + k;
    dsth[o] = h;
    dstl[o] = f2bf(v - bf2f(h));
}

__global__ void bsum_kernel(const float* __restrict__ a, const float* __restrict__ b,
                            float* __restrict__ dst, int n) {
    int j = blockIdx.x * blockDim.x + threadIdx.x;
    if (j < n) dst[j] = a[j] + b[j];
}

// ---------------- GCN aggregation (gather, pure sum), bf16-pair or f32 input ----------------
template<int F, bool PAIRIN>
__global__ __launch_bounds__(F) void gcn_gather_kernel(
        const float* __restrict__ hf, const unsigned short* __restrict__ hih,
        const unsigned short* __restrict__ hil, int ldh, int cofh,
        const float* __restrict__ dinv, const int* __restrict__ off,
        const int* __restrict__ csr_src,
        unsigned short* __restrict__ outh, unsigned short* __restrict__ outl,
        int ldo, int cofo) {
    const int n = blockIdx.x;
    const int j = threadIdx.x;
    float dd = dinv[n];
    auto val = [&](int row) -> float {
        if (PAIRIN) {
            size_t o = (size_t)row * ldh + cofh + j;
            return bf2f(hih[o]) + bf2f(hil[o]);
        } else {
            return hf[(size_t)row * ldh + j];
        }
    };
    float acc = val(n) * dd * dd;
    const int e1 = off[n + 1];
    int e = off[n];
    for (; e + 4 <= e1; e += 4) {
        int s0 = csr_src[e], s1 = csr_src[e + 1], s2 = csr_src[e + 2], s3 = csr_src[e + 3];
        float n0 = dinv[s0] * dd, n1 = dinv[s1] * dd, n2 = dinv[s2] * dd, n3 = dinv[s3] * dd;
        float h0 = val(s0), h1 = val(s1), h2 = val(s2), h3 = val(s3);
        acc += h0 * n0; acc += h1 * n1; acc += h2 * n2; acc += h3 * n3;
    }
    for (; e < e1; ++e) {
        int s0 = csr_src[e];
        acc += val(s0) * (dinv[s0] * dd);
    }
    size_t o = (size_t)n * ldo + cofo + j;
    unsigned short hv = f2bf(acc);
    outh[o] = hv;
    outl[o] = f2bf(acc - bf2f(hv));
}

// ---------------- split-bf16 MFMA GEMM with transposed W ----------------
// A: [M][lda] hi/lo bf16 (reads cols 0..K); Wt: [col][ldt=K] hi/lo bf16.
// Out: optional f32 C (ldc, +zoff for split-K), optional bf16 pair (ldo, coff).
__global__ __launch_bounds__(256) void mfma_gemm_kernel(
        const unsigned short* __restrict__ Ah, const unsigned short* __restrict__ Al, int lda,
        const unsigned short* __restrict__ Wth, const unsigned short* __restrict__ Wtl, int ldt,
        const float* __restrict__ bias,
        float* __restrict__ Cf32, int ldc,
        unsigned short* __restrict__ outh, unsigned short* __restrict__ outl, int ldo, int coff,
        int M, int K, int NW, int relu, int kchunk) {
    __shared__ unsigned short AsH[128 * 40];
    __shared__ unsigned short AsL[128 * 40];
    __shared__ unsigned short WsH[128 * 40];
    __shared__ unsigned short WsL[128 * 40];
    const int tid = threadIdx.x;
    const int row0 = blockIdx.x * 128;
    const int col0 = blockIdx.y * 128;
    int kbeg = 0, kend = K;
    size_t zoff = 0;
    if (kchunk) {
        kbeg = blockIdx.z * kchunk;
        kend = kbeg + kchunk;
        zoff = (size_t)blockIdx.z * M * NW;
    }
    const int w = tid >> 6, l = tid & 63;
    const int wm = w >> 1, wn = w & 1;
    const int lrow = l & 15, lk = l >> 4;
    f32x4 acc[4][4] = {};
    for (int k0 = kbeg; k0 < kend; k0 += 32) {
        #pragma unroll
        for (int i = 0; i < 2; ++i) {
            int c = tid * 2 + i;              // 0..511
            int r = c >> 2, kq = c & 3;
            int gr = row0 + r;
            uint4 vh = make_uint4(0, 0, 0, 0), vl = make_uint4(0, 0, 0, 0);
            if (gr < M) {
                size_t g = (size_t)gr * lda + k0 + kq * 8;
                vh = *(const uint4*)&Ah[g];
                vl = *(const uint4*)&Al[g];
            }
            *(uint4*)&AsH[r * 40 + kq * 8] = vh;
            *(uint4*)&AsL[r * 40 + kq * 8] = vl;
        }
        #pragma unroll
        for (int i = 0; i < 2; ++i) {
            int c = tid + i * 256;            // 0..511
            int col = c & 127, kq = c >> 7;
            size_t g = (size_t)(col0 + col) * ldt + k0 + kq * 8;
            uint4 vh = *(const uint4*)&Wth[g];
            uint4 vl = *(const uint4*)&Wtl[g];
            *(uint4*)&WsH[col * 40 + kq * 8] = vh;
            *(uint4*)&WsL[col * 40 + kq * 8] = vl;
        }
        __syncthreads();
        bf16x8 aH[4], aL[4], bH[4], bL[4];
        #pragma unroll
        for (int mi = 0; mi < 4; ++mi) {
            int r = wm * 64 + mi * 16 + lrow;
            aH[mi] = *(const bf16x8*)&AsH[r * 40 + lk * 8];
            aL[mi] = *(const bf16x8*)&AsL[r * 40 + lk * 8];
        }
        #pragma unroll
        for (int ni = 0; ni < 4; ++ni) {
            int cc = wn * 64 + ni * 16 + lrow;
            bH[ni] = *(const bf16x8*)&WsH[cc * 40 + lk * 8];
            bL[ni] = *(const bf16x8*)&WsL[cc * 40 + lk * 8];
        }
        #pragma unroll
        for (int mi = 0; mi < 4; ++mi)
            #pragma unroll
            for (int ni = 0; ni < 4; ++ni) {
                acc[mi][ni] = __builtin_amdgcn_mfma_f32_16x16x32_bf16(aH[mi], bH[ni], acc[mi][ni], 0, 0, 0);
                acc[mi][ni] = __builtin_amdgcn_mfma_f32_16x16x32_bf16(aH[mi], bL[ni], acc[mi][ni], 0, 0, 0);
                acc[mi][ni] = __builtin_amdgcn_mfma_f32_16x16x32_bf16(aL[mi], bH[ni], acc[mi][ni], 0, 0, 0);
            }
        __syncthreads();
    }
    #pragma unroll
    for (int mi = 0; mi < 4; ++mi) {
        #pragma unroll
        for (int ni = 0; ni < 4; ++ni) {
            int gc = col0 + wn * 64 + ni * 16 + lrow;
            float bb = bias ? bias[gc] : 0.f;
            #pragma unroll
            for (int q = 0; q < 4; ++q) {
                int gr = row0 + wm * 64 + mi * 16 + lk * 4 + q;
                if (gr >= M) continue;
                float v = acc[mi][ni][q] + bb;
                if (relu) v = fmaxf(v, 0.f);
                if (Cf32) Cf32[zoff + (size_t)gr * ldc + gc] = v;
                if (outh) {
                    size_t o = (size_t)gr * ldo + coff + gc;
                    unsigned short hv = f2bf(v);
                    outh[o] = hv;
                    outl[o] = f2bf(v - bf2f(hv));
                }
            }
        }
    }
}

// ---------------- reduce split-K partials + bias + relu ----------------
__global__ void reduce_fp_kernel(const float* __restrict__ part, const float* __restrict__ bias,
                                 float* __restrict__ outp, int total, int stride, int nz) {
    int idx = blockIdx.x * blockDim.x + threadIdx.x;
    if (idx >= total) return;
    float s = 0.f;
    for (int z = 0; z < nz; ++z) s += part[(size_t)z * stride + idx];
    outp[idx] = fmaxf(s + bias[idx & 255], 0.f);
}

// ---------------- fp32 GEMM (tiny fg matmul, K=167) ----------------
__global__ __launch_bounds__(256) void gemm_kernel(
        const float* __restrict__ A, const float* __restrict__ W,
        const float* __restrict__ bias, float* __restrict__ C,
        int M, int K, int N, int do_relu) {
    __shared__ float As[16][128];
    __shared__ float Ws[16][128];
    const int tid = threadIdx.x;
    const int tx = tid & 15;
    const int ty = tid >> 4;
    const int row0 = blockIdx.x * 128;
    const int col0 = blockIdx.y * 128;
    float acc[8][8] = {};
    for (int k0 = 0; k0 < K; k0 += 16) {
        #pragma unroll
        for (int i = 0; i < 2; ++i) {
            int s = tid * 2 + i;
            int r = s >> 2, c = (s & 3) << 2;
            int gr = row0 + r;
            float4 v = make_float4(0.f, 0.f, 0.f, 0.f);
            if (gr < M) {
                if (k0 + c + 3 < K) {
                    v = *(const float4*)(A + (size_t)gr * K + k0 + c);
                } else {
                    float t0 = (k0 + c     < K) ? A[(size_t)gr * K + k0 + c    ] : 0.f;
                    float t1 = (k0 + c + 1 < K) ? A[(size_t)gr * K + k0 + c + 1] : 0.f;
                    float t2 = (k0 + c + 2 < K) ? A[(size_t)gr * K + k0 + c + 2] : 0.f;
                    float t3 = (k0 + c + 3 < K) ? A[(size_t)gr * K + k0 + c + 3] : 0.f;
                    v = make_float4(t0, t1, t2, t3);
                }
            }
            As[c + 0][r] = v.x; As[c + 1][r] = v.y; As[c + 2][r] = v.z; As[c + 3][r] = v.w;
        }
        #pragma unroll
        for (int i = 0; i < 2; ++i) {
            int s = tid * 2 + i;
            int kk = s >> 5, c = (s & 31) << 2;
            int gk = k0 + kk, gc = col0 + c;
            float4 v = make_float4(0.f, 0.f, 0.f, 0.f);
            if (gk < K && gc + 3 < N) v = *(const float4*)(W + (size_t)gk * N + gc);
            *(float4*)&Ws[kk][c] = v;
        }
        __syncthreads();
        #pragma unroll
        for (int kk = 0; kk < 16; ++kk) {
            float a[8], b[8];
            *(float4*)&a[0] = *(const float4*)&As[kk][ty * 4];
            *(float4*)&a[4] = *(const float4*)&As[kk][ty * 4 + 64];
            *(float4*)&b[0] = *(const float4*)&Ws[kk][tx * 4];
            *(float4*)&b[4] = *(const float4*)&Ws[kk][tx * 4 + 64];
            #pragma unroll
            for (int i2 = 0; i2 < 8; ++i2)
                #pragma unroll
                for (int j2 = 0; j2 < 8; ++j2)
                    acc[i2][j2] += a[i2] * b[j2];
        }
        __syncthreads();
    }
    #pragma unroll
    for (int rh = 0; rh < 2; ++rh)
        #pragma unroll
        for (int ii = 0; ii < 4; ++ii) {
            int gr = row0 + ty * 4 + rh * 64 + ii;
            if (gr >= M) continue;
            #pragma unroll
            for (int ch = 0; ch < 2; ++ch) {
                int gc = col0 + tx * 4 + ch * 64;
                float v[4];
                #pragma unroll
                for (int q = 0; q < 4; ++q) {
                    v[q] = acc[rh * 4 + ii][ch * 4 + q] + (bias ? bias[gc + q] : 0.f);
                    if (do_relu) v[q] = fmaxf(v[q], 0.f);
                }
                if (gc + 3 < N)
                    *(float4*)(C + (size_t)gr * N + gc) = make_float4(v[0], v[1], v[2], v[3]);
            }
        }
}

// ---------------- softmax over 256 cols ----------------
__global__ void softmax256_kernel(float* __restrict__ X, int M) {
    int row = blockIdx.x * 4 + (threadIdx.x >> 6);
    int lane = threadIdx.x & 63;
    if (row >= M) return;
    float* p = X + (size_t)row * 256;
    float v0 = p[lane], v1 = p[lane + 64], v2 = p[lane + 128], v3 = p[lane + 192];
    float m = fmaxf(fmaxf(v0, v1), fmaxf(v2, v3));
    for (int off = 32; off; off >>= 1) m = fmaxf(m, __shfl_xor(m, off));
    v0 = expf(v0 - m); v1 = expf(v1 - m); v2 = expf(v2 - m); v3 = expf(v3 - m);
    float s = v0 + v1 + v2 + v3;
    for (int off = 32; off; off >>= 1) s += __shfl_xor(s, off);
    float inv = 1.0f / s;
    p[lane] = v0 * inv; p[lane + 64] = v1 * inv; p[lane + 128] = v2 * inv; p[lane + 192] = v3 * inv;
}

// ---------------- pooling: one block per graph (batch sorted); x3 = hi+lo ----------------
__global__ __launch_bounds__(256) void pool_kernel(
        const float* __restrict__ attn, const unsigned short* __restrict__ x3h,
        const unsigned short* __restrict__ x3l,
        const int* __restrict__ batch, float* __restrict__ pooled, int N, int B) {
    const int b = blockIdx.x;
    const int j = threadIdx.x;
    int lo = 0, hi = N;
    while (lo < hi) { int m = (lo + hi) >> 1; if (batch[m] < b) lo = m + 1; else hi = m; }
    int s0 = lo;
    hi = N;
    while (lo < hi) { int m = (lo + hi) >> 1; if (batch[m] <= b) lo = m + 1; else hi = m; }
    int s1 = lo;
    float acc = 0.f;
    for (int n = s0; n < s1; ++n) {
        size_t o = (size_t)n * 256 + j;
        acc += attn[o] * (bf2f(x3h[o]) + bf2f(x3l[o]));
    }
    float inv = 1.0f / fmaxf((float)(s1 - s0), 1.0f);
    pooled[(size_t)b * 256 + j] = acc * inv;
}

// ---------------- final ----------------
__global__ void final_kernel(const float* __restrict__ pooled, const float* __restrict__ fp,
                             const float* __restrict__ fg, const float* __restrict__ Wfc,
                             const float* __restrict__ bfc, float* __restrict__ out, int B) {
    int b = blockIdx.x * 4 + (threadIdx.x >> 6);
    int lane = threadIdx.x & 63;
    if (b >= B) return;
    float acc = 0.0f;
    #pragma unroll
    for (int i = 0; i < 4; ++i) {
        int j = lane + i * 64;
        size_t o = (size_t)b * 256 + j;
        acc += (pooled[o] + fp[o] + fg[o]) * Wfc[j];
    }
    for (int off = 32; off; off >>= 1) acc += __shfl_xor(acc, off);
    if (lane == 0) out[b] = acc + bfc[0];
}

extern "C" void kernel_launch(void* const* d_in, const int* in_sizes, int n_in,
                              void* d_out, int out_size, void* d_ws, size_t ws_size,
                              hipStream_t stream) {
    const float* x     = (const float*)d_in[0];
    const int*   ei    = (const int*)d_in[1];
    const int*   batch = (const int*)d_in[2];
    const float* fpin  = (const float*)d_in[3];
    const float* fgin  = (const float*)d_in[4];
    const float* W1  = (const float*)d_in[5];  const float* b1  = (const float*)d_in[6];
    const float* W2  = (const float*)d_in[7];  const float* b2  = (const float*)d_in[8];
    const float* W3  = (const float*)d_in[9];  const float* b3  = (const float*)d_in[10];
    const float* Wr1 = (const float*)d_in[11]; const float* br1 = (const float*)d_in[12];
    const float* Wr2 = (const float*)d_in[13]; const float* br2 = (const float*)d_in[14];
    const float* Wfp = (const float*)d_in[15]; const float* bfp = (const float*)d_in[16];
    const float* Wfg = (const float*)d_in[17]; const float* bfg = (const float*)d_in[18];
    const float* attnW = (const float*)d_in[19];
    const float* Wfc = (const float*)d_in[20]; const float* bfc = (const float*)d_in[21];
    float* out = (float*)d_out;

    const int Nn = in_sizes[0] / 64;
    const int E  = in_sizes[1] / 2;
    const int B  = in_sizes[3] / 2048;
    const int* src = ei;
    const int* dst = ei + E;

    char* wsb = (char*)d_ws;
    size_t woff = 0;
    auto alloc = [&](size_t bytes) -> void* {
        void* p = wsb + woff;
        woff += (bytes + 255) & ~(size_t)255;
        return p;
    };

    // ---- persistent ----
    int*   deg_i   = (int*)alloc((size_t)Nn * 4);
    int*   pos     = (int*)alloc((size_t)Nn * 4);
    int*   offv    = (int*)alloc(((size_t)Nn + 1) * 4);
    float* dinv    = (float*)alloc((size_t)Nn * 4);
    int*   csr_src = (int*)alloc((size_t)E * 4);
    unsigned short* W1th  = (unsigned short*)alloc(64 * 128 * 2);
    unsigned short* W1tl  = (unsigned short*)alloc(64 * 128 * 2);
    unsigned short* Wc2th = (unsigned short*)alloc(256 * 256 * 2);
    unsigned short* Wc2tl = (unsigned short*)alloc(256 * 256 * 2);
    unsigned short* Wc3th = (unsigned short*)alloc(512 * 256 * 2);
    unsigned short* Wc3tl = (unsigned short*)alloc(512 * 256 * 2);
    unsigned short* aWth  = (unsigned short*)alloc(256 * 256 * 2);
    unsigned short* aWtl  = (unsigned short*)alloc(256 * 256 * 2);
    unsigned short* Wfpth = (unsigned short*)alloc(2048 * 256 * 2);
    unsigned short* Wfptl = (unsigned short*)alloc(2048 * 256 * 2);
    float* bsum2 = (float*)alloc(256 * 4);
    float* bsum3 = (float*)alloc(256 * 4);
    // ---- regions ----
    unsigned short* Acat2h = (unsigned short*)alloc((size_t)Nn * 256 * 2);  // 25.6 MB
    unsigned short* Acat2l = (unsigned short*)alloc((size_t)Nn * 256 * 2);
    unsigned short* Acat3h = (unsigned short*)alloc((size_t)Nn * 512 * 2);  // 51.2 MB
    unsigned short* Acat3l = (unsigned short*)alloc((size_t)Nn * 512 * 2);
    unsigned short* x3h    = (unsigned short*)alloc((size_t)Nn * 256 * 2);
    unsigned short* x3l    = (unsigned short*)alloc((size_t)Nn * 256 * 2);
    (void)ws_size; (void)n_in; (void)out_size;

    // ---- overlays ----
    // agg0 pair (Nn x 64): lives gather0 -> GEMM1; occupies head of Acat3h/Acat3l (dead until L2 GEMM).
    unsigned short* agg0h = Acat3h;
    unsigned short* agg0l = Acat3l;
    // after L3 GEMM, Acat3 region is dead:
    float* logits = (float*)Acat3h;                                   // Nn x 256 f32 = 51.2 MB
    char* fpRegion = (char*)Acat3l;
    unsigned short* fpinh = (unsigned short*)(fpRegion);              // B x 2048 bf16 = 4.19 MB
    unsigned short* fpinl = (unsigned short*)(fpRegion + 4500000 - (4500000 % 256));
    float* part   = (float*)(fpRegion + 9000192);                     // 8 x B x 256 f32 = 8.39 MB
    float* fpb    = (float*)(fpRegion + 17500160);
    float* fgb    = (float*)(fpRegion + 18600192);
    float* pooled = (float*)(fpRegion + 19700224);

    // ---- CSR build ----
    hipMemsetAsync(deg_i, 0, (size_t)Nn * 4, stream);
    hipMemsetAsync(pos,   0, (size_t)Nn * 4, stream);
    deg_count_kernel<<<CDIV(E, 256), 256, 0, stream>>>(dst, deg_i, E);
    dinv_kernel<<<CDIV(Nn, 256), 256, 0, stream>>>(deg_i, dinv, Nn);
    scan_kernel<<<1, 1024, 0, stream>>>(deg_i, offv, Nn, E);
    csr_fill_kernel<<<CDIV(E, 256), 256, 0, stream>>>(src, dst, offv, pos, csr_src, E);

    // ---- weight transpose-splits ----
    wsplit_t_kernel<<<CDIV(64 * 128, 256), 256, 0, stream>>>(W1, 64, 128, W1th, W1tl, 64, 0);
    wsplit_t_kernel<<<CDIV(128 * 256, 256), 256, 0, stream>>>(W2,  128, 256, Wc2th, Wc2tl, 256, 0);
    wsplit_t_kernel<<<CDIV(128 * 256, 256), 256, 0, stream>>>(Wr1, 128, 256, Wc2th, Wc2tl, 256, 128);
    wsplit_t_kernel<<<CDIV(256 * 256, 256), 256, 0, stream>>>(W3,  256, 256, Wc3th, Wc3tl, 512, 0);
    wsplit_t_kernel<<<CDIV(256 * 256, 256), 256, 0, stream>>>(Wr2, 256, 256, Wc3th, Wc3tl, 512, 256);
    wsplit_t_kernel<<<CDIV(256 * 256, 256), 256, 0, stream>>>(attnW, 256, 256, aWth, aWtl, 256, 0);
    wsplit_t_kernel<<<CDIV(2048 * 256, 256), 256, 0, stream>>>(Wfp, 2048, 256, Wfpth, Wfptl, 2048, 0);
    bsum_kernel<<<1, 256, 0, stream>>>(b2, br1, bsum2, 256);
    bsum_kernel<<<1, 256, 0, stream>>>(b3, br2, bsum3, 256);

    const int MB = CDIV(Nn, 128);

    // ---- layer 1: agg0 = Agg(x); x1 = relu(agg0 @ W1 + b1) -> Acat2[:,128:256] ----
    gcn_gather_kernel<64, false><<<Nn, 64, 0, stream>>>(x, nullptr, nullptr, 64, 0,
                                                        dinv, offv, csr_src, agg0h, agg0l, 64, 0);
    mfma_gemm_kernel<<<dim3(MB, 1), 256, 0, stream>>>(agg0h, agg0l, 64, W1th, W1tl, 64,
                                                      b1, nullptr, 0, Acat2h, Acat2l, 256, 128,
                                                      Nn, 64, 128, 1, 0);

    // ---- layer 2: agg1 = Agg(x1) -> Acat2[:,0:128]; x2 = relu(Acat2 @ [W2;Wr1] + b2+br1) ----
    gcn_gather_kernel<128, true><<<Nn, 128, 0, stream>>>(nullptr, Acat2h, Acat2l, 256, 128,
                                                         dinv, offv, csr_src, Acat2h, Acat2l, 256, 0);
    mfma_gemm_kernel<<<dim3(MB, 2), 256, 0, stream>>>(Acat2h, Acat2l, 256, Wc2th, Wc2tl, 256,
                                                      bsum2, nullptr, 0, Acat3h, Acat3l, 512, 256,
                                                      Nn, 256, 256, 1, 0);

    // ---- layer 3: agg2 = Agg(x2) -> Acat3[:,0:256]; x3 = relu(Acat3 @ [W3;Wr2] + b3+br2) ----
    gcn_gather_kernel<256, true><<<Nn, 256, 0, stream>>>(nullptr, Acat3h, Acat3l, 512, 256,
                                                         dinv, offv, csr_src, Acat3h, Acat3l, 512, 0);
    mfma_gemm_kernel<<<dim3(MB, 2), 256, 0, stream>>>(Acat3h, Acat3l, 512, Wc3th, Wc3tl, 512,
                                                      bsum3, nullptr, 0, x3h, x3l, 256, 0,
                                                      Nn, 512, 256, 1, 0);

    // ---- attention logits (Acat3 dead now; logits overlays it) ----
    mfma_gemm_kernel<<<dim3(MB, 2), 256, 0, stream>>>(x3h, x3l, 256, aWth, aWtl, 256,
                                                      nullptr, logits, 256, nullptr, nullptr, 0, 0,
                                                      Nn, 256, 256, 0, 0);

    // ---- fp MLP (split-K x8) ----
    long long tfp = (long long)B * 2048;
    split_kernel<<<CDIV(tfp, 256), 256, 0, stream>>>(fpin, fpinh, fpinl, tfp);
    mfma_gemm_kernel<<<dim3(CDIV(B, 128), 2, 8), 256, 0, stream>>>(fpinh, fpinl, 2048, Wfpth, Wfptl, 2048,
                                                                   nullptr, part, 256, nullptr, nullptr, 0, 0,
                                                                   B, 2048, 256, 0, 256);
    reduce_fp_kernel<<<CDIV(B * 256, 256), 256, 0, stream>>>(part, bfp, fpb, B * 256, B * 256, 8);

    // ---- fg MLP (tiny, fp32 path) ----
    gemm_kernel<<<dim3(CDIV(B, 128), 2), 256, 0, stream>>>(fgin, Wfg, bfg, fgb, B, 167, 256, 1);

    // ---- softmax + pooling + final ----
    softmax256_kernel<<<CDIV(Nn, 4), 256, 0, stream>>>(logits, Nn);
    pool_kernel<<<B, 256, 0, stream>>>(logits, x3h, x3l, batch, pooled, Nn, B);
    final_kernel<<<CDIV(B, 4), 256, 0, stream>>>(pooled, fpb, fgb, Wfc, bfc, out, B);
}

// Round 7
// 759.808 us; speedup vs baseline: 4.3626x; 1.1032x over previous
//
#include <hip/hip_runtime.h>
#include <math.h>

#define CDIV(a,b) (((a)+(b)-1)/(b))

typedef __attribute__((ext_vector_type(8))) short bf16x8;
typedef __attribute__((ext_vector_type(4))) float f32x4;

__device__ inline unsigned short f2bf(float f) {           // RNE bf16
    unsigned int u = __float_as_uint(f);
    u += 0x7fffu + ((u >> 16) & 1u);
    return (unsigned short)(u >> 16);
}
__device__ inline float bf2f(unsigned short h) { return __uint_as_float(((unsigned int)h) << 16); }
__device__ inline unsigned short f2h(float f) {
    _Float16 h = (_Float16)f;
    return *(unsigned short*)&h;
}
__device__ inline float h2f(unsigned short u) {
    _Float16 h = *(_Float16*)&u;
    return (float)h;
}

// ---------------- degree / dinv ----------------
__global__ void deg_count_kernel(const int* __restrict__ dst, int* __restrict__ deg, int E) {
    int e = blockIdx.x * blockDim.x + threadIdx.x;
    if (e < E) atomicAdd(&deg[dst[e]], 1);
}

__global__ void dinv_kernel(const int* __restrict__ deg, float* __restrict__ dinv, int N) {
    int i = blockIdx.x * blockDim.x + threadIdx.x;
    if (i < N) dinv[i] = rsqrtf((float)deg[i] + 1.0f);
}

// ---------------- parallel scan: chunk sums -> scan chunks -> apply ----------------
__global__ void chunk_sum_kernel(const int* __restrict__ deg, int* __restrict__ csum, int N) {
    __shared__ int ws[4];
    int c = blockIdx.x, t = threadIdx.x;          // 256 threads
    int base = c * 1024;
    int s = 0;
    for (int i = t; i < 1024; i += 256) { int idx = base + i; s += (idx < N) ? deg[idx] : 0; }
    for (int o = 32; o; o >>= 1) s += __shfl_xor(s, o);
    if ((t & 63) == 0) ws[t >> 6] = s;
    __syncthreads();
    if (t == 0) csum[c] = ws[0] + ws[1] + ws[2] + ws[3];
}

__global__ void chunk_scan_kernel(int* __restrict__ csum, int nc) {   // 1 block, 64 threads, nc<=64
    int t = threadIdx.x;
    int v = (t < nc) ? csum[t] : 0;
    int x = v;
    #pragma unroll
    for (int o = 1; o < 64; o <<= 1) { int y = __shfl_up(x, o, 64); if (t >= o) x += y; }
    if (t < nc) csum[t] = x - v;                  // exclusive
}

__global__ void chunk_scan_apply_kernel(const int* __restrict__ deg, const int* __restrict__ cbase,
                                        int* __restrict__ off, int N, int E) {
    __shared__ int wsum[16];
    int c = blockIdx.x;
    int t = threadIdx.x;                          // 1024 threads
    int lane = t & 63, wid = t >> 6;
    int i = c * 1024 + t;
    int v = (i < N) ? deg[i] : 0;
    int x = v;
    #pragma unroll
    for (int o = 1; o < 64; o <<= 1) { int y = __shfl_up(x, o, 64); if (lane >= o) x += y; }
    if (lane == 63) wsum[wid] = x;
    __syncthreads();
    if (wid == 0) {
        int wv = (lane < 16) ? wsum[lane] : 0;
        #pragma unroll
        for (int o = 1; o < 16; o <<= 1) { int y = __shfl_up(wv, o, 64); if (lane >= o) wv += y; }
        if (lane < 16) wsum[lane] = wv;
    }
    __syncthreads();
    int wexcl = wid ? wsum[wid - 1] : 0;
    if (i < N) off[i] = cbase[c] + wexcl + x - v;
    if (i == N) off[N] = E;    // exists since N < gridDim.x*1024 here (N=50000, 49*1024=50176)
}

// ---------------- CSR fill ----------------
__global__ void csr_fill_kernel(const int* __restrict__ src, const int* __restrict__ dst,
                                const int* __restrict__ off, int* __restrict__ pos,
                                int* __restrict__ csr_src, int E) {
    int e = blockIdx.x * blockDim.x + threadIdx.x;
    if (e >= E) return;
    int s = src[e], d = dst[e];
    int p = off[d] + atomicAdd(&pos[d], 1);
    csr_src[p] = s;
}

// ---------------- split fp32 -> (hi,lo) bf16 ----------------
__global__ void split_kernel(const float* __restrict__ src, unsigned short* __restrict__ hi,
                             unsigned short* __restrict__ lo, long long total) {
    long long idx = (long long)blockIdx.x * blockDim.x + threadIdx.x;
    if (idx >= total) return;
    float v = src[idx];
    unsigned short h = f2bf(v);
    hi[idx] = h;
    lo[idx] = f2bf(v - bf2f(h));
}

__global__ void f32_to_f16_kernel(const float* __restrict__ src, unsigned short* __restrict__ dst,
                                  long long total) {
    long long idx = (long long)blockIdx.x * blockDim.x + threadIdx.x;
    if (idx >= total) return;
    dst[idx] = f2h(src[idx]);
}

// ---------------- transpose-split weights: src[K][N] -> dst[col][koff+k] (ldt) ----------------
__global__ void wsplit_t_kernel(const float* __restrict__ src, int K, int N,
                                unsigned short* __restrict__ dsth, unsigned short* __restrict__ dstl,
                                int ldt, int koff) {
    int idx = blockIdx.x * blockDim.x + threadIdx.x;
    if (idx >= K * N) return;
    int col = idx / K;
    int k = idx - col * K;
    float v = src[(size_t)k * N + col];
    unsigned short h = f2bf(v);
    size_t o = (size_t)col * ldt + koff + k;
    dsth[o] = h;
    dstl[o] = f2bf(v - bf2f(h));
}

__global__ void bsum_kernel(const float* __restrict__ a, const float* __restrict__ b,
                            float* __restrict__ dst, int n) {
    int j = blockIdx.x * blockDim.x + threadIdx.x;
    if (j < n) dst[j] = a[j] + b[j];
}

// ---------------- GCN aggregation (gather, pure sum): fp16 in -> bf16 pair out ----------------
template<int F>
__global__ __launch_bounds__(F) void gcn_gather_kernel(
        const unsigned short* __restrict__ h16, int ldh,
        const float* __restrict__ dinv, const int* __restrict__ off,
        const int* __restrict__ csr_src,
        unsigned short* __restrict__ outh, unsigned short* __restrict__ outl,
        int ldo, int cofo) {
    const int n = blockIdx.x;
    const int j = threadIdx.x;
    float dd = dinv[n];
    float acc = h2f(h16[(size_t)n * ldh + j]) * dd * dd;
    const int e1 = off[n + 1];
    int e = off[n];
    for (; e + 4 <= e1; e += 4) {
        int s0 = csr_src[e], s1 = csr_src[e + 1], s2 = csr_src[e + 2], s3 = csr_src[e + 3];
        float n0 = dinv[s0] * dd, n1 = dinv[s1] * dd, n2 = dinv[s2] * dd, n3 = dinv[s3] * dd;
        float h0 = h2f(h16[(size_t)s0 * ldh + j]);
        float h1 = h2f(h16[(size_t)s1 * ldh + j]);
        float h2 = h2f(h16[(size_t)s2 * ldh + j]);
        float h3 = h2f(h16[(size_t)s3 * ldh + j]);
        acc += h0 * n0; acc += h1 * n1; acc += h2 * n2; acc += h3 * n3;
    }
    for (; e < e1; ++e) {
        int s0 = csr_src[e];
        acc += h2f(h16[(size_t)s0 * ldh + j]) * (dinv[s0] * dd);
    }
    size_t o = (size_t)n * ldo + cofo + j;
    unsigned short hv = f2bf(acc);
    outh[o] = hv;
    outl[o] = f2bf(acc - bf2f(hv));
}

// ---------------- split-bf16 MFMA GEMM with transposed W ----------------
// Outputs (each optional): f32 C (ldc, +zoff split-K), bf16 pair (ldo,coff), fp16 (ldo16).
__global__ __launch_bounds__(256) void mfma_gemm_kernel(
        const unsigned short* __restrict__ Ah, const unsigned short* __restrict__ Al, int lda,
        const unsigned short* __restrict__ Wth, const unsigned short* __restrict__ Wtl, int ldt,
        const float* __restrict__ bias,
        float* __restrict__ Cf32, int ldc,
        unsigned short* __restrict__ outh, unsigned short* __restrict__ outl, int ldo, int coff,
        unsigned short* __restrict__ outf16, int ldo16,
        int M, int K, int NW, int relu, int kchunk) {
    __shared__ unsigned short AsH[128 * 40];
    __shared__ unsigned short AsL[128 * 40];
    __shared__ unsigned short WsH[128 * 40];
    __shared__ unsigned short WsL[128 * 40];
    const int tid = threadIdx.x;
    const int row0 = blockIdx.x * 128;
    const int col0 = blockIdx.y * 128;
    int kbeg = 0, kend = K;
    size_t zoff = 0;
    if (kchunk) {
        kbeg = blockIdx.z * kchunk;
        kend = kbeg + kchunk;
        zoff = (size_t)blockIdx.z * M * NW;
    }
    const int w = tid >> 6, l = tid & 63;
    const int wm = w >> 1, wn = w & 1;
    const int lrow = l & 15, lk = l >> 4;
    f32x4 acc[4][4] = {};
    for (int k0 = kbeg; k0 < kend; k0 += 32) {
        #pragma unroll
        for (int i = 0; i < 2; ++i) {
            int c = tid * 2 + i;              // 0..511
            int r = c >> 2, kq = c & 3;
            int gr = row0 + r;
            uint4 vh = make_uint4(0, 0, 0, 0), vl = make_uint4(0, 0, 0, 0);
            if (gr < M) {
                size_t g = (size_t)gr * lda + k0 + kq * 8;
                vh = *(const uint4*)&Ah[g];
                vl = *(const uint4*)&Al[g];
            }
            *(uint4*)&AsH[r * 40 + kq * 8] = vh;
            *(uint4*)&AsL[r * 40 + kq * 8] = vl;
        }
        #pragma unroll
        for (int i = 0; i < 2; ++i) {
            int c = tid + i * 256;            // 0..511
            int col = c & 127, kq = c >> 7;
            size_t g = (size_t)(col0 + col) * ldt + k0 + kq * 8;
            uint4 vh = *(const uint4*)&Wth[g];
            uint4 vl = *(const uint4*)&Wtl[g];
            *(uint4*)&WsH[col * 40 + kq * 8] = vh;
            *(uint4*)&WsL[col * 40 + kq * 8] = vl;
        }
        __syncthreads();
        bf16x8 aH[4], aL[4], bH[4], bL[4];
        #pragma unroll
        for (int mi = 0; mi < 4; ++mi) {
            int r = wm * 64 + mi * 16 + lrow;
            aH[mi] = *(const bf16x8*)&AsH[r * 40 + lk * 8];
            aL[mi] = *(const bf16x8*)&AsL[r * 40 + lk * 8];
        }
        #pragma unroll
        for (int ni = 0; ni < 4; ++ni) {
            int cc = wn * 64 + ni * 16 + lrow;
            bH[ni] = *(const bf16x8*)&WsH[cc * 40 + lk * 8];
            bL[ni] = *(const bf16x8*)&WsL[cc * 40 + lk * 8];
        }
        #pragma unroll
        for (int mi = 0; mi < 4; ++mi)
            #pragma unroll
            for (int ni = 0; ni < 4; ++ni) {
                acc[mi][ni] = __builtin_amdgcn_mfma_f32_16x16x32_bf16(aH[mi], bH[ni], acc[mi][ni], 0, 0, 0);
                acc[mi][ni] = __builtin_amdgcn_mfma_f32_16x16x32_bf16(aH[mi], bL[ni], acc[mi][ni], 0, 0, 0);
                acc[mi][ni] = __builtin_amdgcn_mfma_f32_16x16x32_bf16(aL[mi], bH[ni], acc[mi][ni], 0, 0, 0);
            }
        __syncthreads();
    }
    #pragma unroll
    for (int mi = 0; mi < 4; ++mi) {
        #pragma unroll
        for (int ni = 0; ni < 4; ++ni) {
            int gc = col0 + wn * 64 + ni * 16 + lrow;
            float bb = bias ? bias[gc] : 0.f;
            #pragma unroll
            for (int q = 0; q < 4; ++q) {
                int gr = row0 + wm * 64 + mi * 16 + lk * 4 + q;
                if (gr >= M) continue;
                float v = acc[mi][ni][q] + bb;
                if (relu) v = fmaxf(v, 0.f);
                if (Cf32) Cf32[zoff + (size_t)gr * ldc + gc] = v;
                if (outh) {
                    size_t o = (size_t)gr * ldo + coff + gc;
                    unsigned short hv = f2bf(v);
                    outh[o] = hv;
                    outl[o] = f2bf(v - bf2f(hv));
                }
                if (outf16) outf16[(size_t)gr * ldo16 + gc] = f2h(v);
            }
        }
    }
}

// ---------------- reduce split-K partials + bias + relu ----------------
__global__ void reduce_fp_kernel(const float* __restrict__ part, const float* __restrict__ bias,
                                 float* __restrict__ outp, int total, int stride, int nz) {
    int idx = blockIdx.x * blockDim.x + threadIdx.x;
    if (idx >= total) return;
    float s = 0.f;
    for (int z = 0; z < nz; ++z) s += part[(size_t)z * stride + idx];
    outp[idx] = fmaxf(s + bias[idx & 255], 0.f);
}

// ---------------- fp32 GEMM (tiny fg matmul, K=167) ----------------
__global__ __launch_bounds__(256) void gemm_kernel(
        const float* __restrict__ A, const float* __restrict__ W,
        const float* __restrict__ bias, float* __restrict__ C,
        int M, int K, int N, int do_relu) {
    __shared__ float As[16][128];
    __shared__ float Ws[16][128];
    const int tid = threadIdx.x;
    const int tx = tid & 15;
    const int ty = tid >> 4;
    const int row0 = blockIdx.x * 128;
    const int col0 = blockIdx.y * 128;
    float acc[8][8] = {};
    for (int k0 = 0; k0 < K; k0 += 16) {
        #pragma unroll
        for (int i = 0; i < 2; ++i) {
            int s = tid * 2 + i;
            int r = s >> 2, c = (s & 3) << 2;
            int gr = row0 + r;
            float4 v = make_float4(0.f, 0.f, 0.f, 0.f);
            if (gr < M) {
                if (k0 + c + 3 < K) {
                    v = *(const float4*)(A + (size_t)gr * K + k0 + c);
                } else {
                    float t0 = (k0 + c     < K) ? A[(size_t)gr * K + k0 + c    ] : 0.f;
                    float t1 = (k0 + c + 1 < K) ? A[(size_t)gr * K + k0 + c + 1] : 0.f;
                    float t2 = (k0 + c + 2 < K) ? A[(size_t)gr * K + k0 + c + 2] : 0.f;
                    float t3 = (k0 + c + 3 < K) ? A[(size_t)gr * K + k0 + c + 3] : 0.f;
                    v = make_float4(t0, t1, t2, t3);
                }
            }
            As[c + 0][r] = v.x; As[c + 1][r] = v.y; As[c + 2][r] = v.z; As[c + 3][r] = v.w;
        }
        #pragma unroll
        for (int i = 0; i < 2; ++i) {
            int s = tid * 2 + i;
            int kk = s >> 5, c = (s & 31) << 2;
            int gk = k0 + kk, gc = col0 + c;
            float4 v = make_float4(0.f, 0.f, 0.f, 0.f);
            if (gk < K && gc + 3 < N) v = *(const float4*)(W + (size_t)gk * N + gc);
            *(float4*)&Ws[kk][c] = v;
        }
        __syncthreads();
        #pragma unroll
        for (int kk = 0; kk < 16; ++kk) {
            float a[8], b[8];
            *(float4*)&a[0] = *(const float4*)&As[kk][ty * 4];
            *(float4*)&a[4] = *(const float4*)&As[kk][ty * 4 + 64];
            *(float4*)&b[0] = *(const float4*)&Ws[kk][tx * 4];
            *(float4*)&b[4] = *(const float4*)&Ws[kk][tx * 4 + 64];
            #pragma unroll
            for (int i2 = 0; i2 < 8; ++i2)
                #pragma unroll
                for (int j2 = 0; j2 < 8; ++j2)
                    acc[i2][j2] += a[i2] * b[j2];
        }
        __syncthreads();
    }
    #pragma unroll
    for (int rh = 0; rh < 2; ++rh)
        #pragma unroll
        for (int ii = 0; ii < 4; ++ii) {
            int gr = row0 + ty * 4 + rh * 64 + ii;
            if (gr >= M) continue;
            #pragma unroll
            for (int ch = 0; ch < 2; ++ch) {
                int gc = col0 + tx * 4 + ch * 64;
                float v[4];
                #pragma unroll
                for (int q = 0; q < 4; ++q) {
                    v[q] = acc[rh * 4 + ii][ch * 4 + q] + (bias ? bias[gc + q] : 0.f);
                    if (do_relu) v[q] = fmaxf(v[q], 0.f);
                }
                if (gc + 3 < N)
                    *(float4*)(C + (size_t)gr * N + gc) = make_float4(v[0], v[1], v[2], v[3]);
            }
        }
}

// ---------------- fused softmax + mean-pool (batch sorted) ----------------
__global__ __launch_bounds__(256) void softmaxpool_kernel(
        const float* __restrict__ logits, const unsigned short* __restrict__ x3f16,
        const int* __restrict__ batch, float* __restrict__ pooled, int N, int B) {
    __shared__ float lacc[4][256];
    const int b = blockIdx.x;
    const int t = threadIdx.x;
    const int lane = t & 63, wid = t >> 6;
    int lo = 0, hi = N;
    while (lo < hi) { int m = (lo + hi) >> 1; if (batch[m] < b) lo = m + 1; else hi = m; }
    int s0 = lo;
    hi = N;
    while (lo < hi) { int m = (lo + hi) >> 1; if (batch[m] <= b) lo = m + 1; else hi = m; }
    int s1 = lo;
    float a0 = 0.f, a1 = 0.f, a2 = 0.f, a3 = 0.f;
    for (int n = s0 + wid; n < s1; n += 4) {
        const float* p = logits + (size_t)n * 256;
        float v0 = p[lane], v1 = p[lane + 64], v2 = p[lane + 128], v3 = p[lane + 192];
        float m = fmaxf(fmaxf(v0, v1), fmaxf(v2, v3));
        for (int o = 32; o; o >>= 1) m = fmaxf(m, __shfl_xor(m, o));
        v0 = expf(v0 - m); v1 = expf(v1 - m); v2 = expf(v2 - m); v3 = expf(v3 - m);
        float s = v0 + v1 + v2 + v3;
        for (int o = 32; o; o >>= 1) s += __shfl_xor(s, o);
        float inv = 1.0f / s;
        const unsigned short* q = x3f16 + (size_t)n * 256;
        a0 += v0 * inv * h2f(q[lane]);
        a1 += v1 * inv * h2f(q[lane + 64]);
        a2 += v2 * inv * h2f(q[lane + 128]);
        a3 += v3 * inv * h2f(q[lane + 192]);
    }
    lacc[wid][lane] = a0; lacc[wid][lane + 64] = a1;
    lacc[wid][lane + 128] = a2; lacc[wid][lane + 192] = a3;
    __syncthreads();
    float tot = lacc[0][t] + lacc[1][t] + lacc[2][t] + lacc[3][t];
    float invc = 1.0f / fmaxf((float)(s1 - s0), 1.0f);
    pooled[(size_t)b * 256 + t] = tot * invc;
}

// ---------------- final ----------------
__global__ void final_kernel(const float* __restrict__ pooled, const float* __restrict__ fp,
                             const float* __restrict__ fg, const float* __restrict__ Wfc,
                             const float* __restrict__ bfc, float* __restrict__ out, int B) {
    int b = blockIdx.x * 4 + (threadIdx.x >> 6);
    int lane = threadIdx.x & 63;
    if (b >= B) return;
    float acc = 0.0f;
    #pragma unroll
    for (int i = 0; i < 4; ++i) {
        int j = lane + i * 64;
        size_t o = (size_t)b * 256 + j;
        acc += (pooled[o] + fp[o] + fg[o]) * Wfc[j];
    }
    for (int off = 32; off; off >>= 1) acc += __shfl_xor(acc, off);
    if (lane == 0) out[b] = acc + bfc[0];
}

extern "C" void kernel_launch(void* const* d_in, const int* in_sizes, int n_in,
                              void* d_out, int out_size, void* d_ws, size_t ws_size,
                              hipStream_t stream) {
    const float* x     = (const float*)d_in[0];
    const int*   ei    = (const int*)d_in[1];
    const int*   batch = (const int*)d_in[2];
    const float* fpin  = (const float*)d_in[3];
    const float* fgin  = (const float*)d_in[4];
    const float* W1  = (const float*)d_in[5];  const float* b1  = (const float*)d_in[6];
    const float* W2  = (const float*)d_in[7];  const float* b2  = (const float*)d_in[8];
    const float* W3  = (const float*)d_in[9];  const float* b3  = (const float*)d_in[10];
    const float* Wr1 = (const float*)d_in[11]; const float* br1 = (const float*)d_in[12];
    const float* Wr2 = (const float*)d_in[13]; const float* br2 = (const float*)d_in[14];
    const float* Wfp = (const float*)d_in[15]; const float* bfp = (const float*)d_in[16];
    const float* Wfg = (const float*)d_in[17]; const float* bfg = (const float*)d_in[18];
    const float* attnW = (const float*)d_in[19];
    const float* Wfc = (const float*)d_in[20]; const float* bfc = (const float*)d_in[21];
    float* out = (float*)d_out;

    const int Nn = in_sizes[0] / 64;
    const int E  = in_sizes[1] / 2;
    const int B  = in_sizes[3] / 2048;
    const int* src = ei;
    const int* dst = ei + E;

    char* wsb = (char*)d_ws;
    size_t woff = 0;
    auto alloc = [&](size_t bytes) -> void* {
        void* p = wsb + woff;
        woff += (bytes + 255) & ~(size_t)255;
        return p;
    };

    // ---- persistent ----
    int*   deg_i   = (int*)alloc((size_t)Nn * 4);
    int*   pos     = (int*)alloc((size_t)Nn * 4);
    int*   offv    = (int*)alloc(((size_t)Nn + 1) * 4);
    float* dinv    = (float*)alloc((size_t)Nn * 4);
    int*   csum    = (int*)alloc(64 * 4);
    int*   csr_src = (int*)alloc((size_t)E * 4);
    unsigned short* W1th  = (unsigned short*)alloc(64 * 128 * 2);
    unsigned short* W1tl  = (unsigned short*)alloc(64 * 128 * 2);
    unsigned short* Wc2th = (unsigned short*)alloc(256 * 256 * 2);
    unsigned short* Wc2tl = (unsigned short*)alloc(256 * 256 * 2);
    unsigned short* Wc3th = (unsigned short*)alloc(512 * 256 * 2);
    unsigned short* Wc3tl = (unsigned short*)alloc(512 * 256 * 2);
    unsigned short* aWth  = (unsigned short*)alloc(256 * 256 * 2);
    unsigned short* aWtl  = (unsigned short*)alloc(256 * 256 * 2);
    unsigned short* Wfpth = (unsigned short*)alloc(2048 * 256 * 2);
    unsigned short* Wfptl = (unsigned short*)alloc(2048 * 256 * 2);
    float* bsum2 = (float*)alloc(256 * 4);
    float* bsum3 = (float*)alloc(256 * 4);
    // ---- regions ----
    unsigned short* Acat2h = (unsigned short*)alloc((size_t)Nn * 256 * 2);  // 25.6 MB
    unsigned short* Acat2l = (unsigned short*)alloc((size_t)Nn * 256 * 2);
    unsigned short* Acat3h = (unsigned short*)alloc((size_t)Nn * 512 * 2);  // 51.2 MB
    unsigned short* Acat3l = (unsigned short*)alloc((size_t)Nn * 512 * 2);
    unsigned short* x3h    = (unsigned short*)alloc((size_t)Nn * 256 * 2);
    unsigned short* x3l    = (unsigned short*)alloc((size_t)Nn * 256 * 2);
    unsigned short* x23f16 = (unsigned short*)alloc((size_t)Nn * 256 * 2);  // x2f16 then x3f16
    (void)ws_size; (void)n_in; (void)out_size;

    // ---- overlays ----
    // phase A of Acat3h: agg0h (Nn*64) at 0, xf16 (Nn*64) at +8MB
    unsigned short* agg0h = Acat3h;
    unsigned short* xf16  = (unsigned short*)((char*)Acat3h + 8388608);
    // phase A of Acat3l: agg0l at 0, x1f16 (Nn*128) at +8MB
    unsigned short* agg0l = Acat3l;
    unsigned short* x1f16 = (unsigned short*)((char*)Acat3l + 8388608);
    // after L3 GEMM, Acat3 dead:
    float* logits = (float*)Acat3h;                                   // Nn x 256 f32
    char* fpRegion = (char*)Acat3l;
    unsigned short* fpinh = (unsigned short*)(fpRegion);
    unsigned short* fpinl = (unsigned short*)(fpRegion + 4499968);
    float* part   = (float*)(fpRegion + 9000192);
    float* fpb    = (float*)(fpRegion + 17500160);
    float* fgb    = (float*)(fpRegion + 18600192);
    float* pooled = (float*)(fpRegion + 19700224);
    unsigned short* x2f16 = x23f16;
    unsigned short* x3f16 = x23f16;   // same region, sequential lifetimes

    // ---- CSR build (parallel scan) ----
    hipMemsetAsync(deg_i, 0, (size_t)Nn * 4, stream);
    hipMemsetAsync(pos,   0, (size_t)Nn * 4, stream);
    deg_count_kernel<<<CDIV(E, 256), 256, 0, stream>>>(dst, deg_i, E);
    dinv_kernel<<<CDIV(Nn, 256), 256, 0, stream>>>(deg_i, dinv, Nn);
    const int NC = CDIV(Nn, 1024);   // 49 for N=50000 (<=64 required)
    chunk_sum_kernel<<<NC, 256, 0, stream>>>(deg_i, csum, Nn);
    chunk_scan_kernel<<<1, 64, 0, stream>>>(csum, NC);
    chunk_scan_apply_kernel<<<NC, 1024, 0, stream>>>(deg_i, csum, offv, Nn, E);
    csr_fill_kernel<<<CDIV(E, 256), 256, 0, stream>>>(src, dst, offv, pos, csr_src, E);

    // ---- weight transpose-splits + input fp16 ----
    wsplit_t_kernel<<<CDIV(64 * 128, 256), 256, 0, stream>>>(W1, 64, 128, W1th, W1tl, 64, 0);
    wsplit_t_kernel<<<CDIV(128 * 256, 256), 256, 0, stream>>>(W2,  128, 256, Wc2th, Wc2tl, 256, 0);
    wsplit_t_kernel<<<CDIV(128 * 256, 256), 256, 0, stream>>>(Wr1, 128, 256, Wc2th, Wc2tl, 256, 128);
    wsplit_t_kernel<<<CDIV(256 * 256, 256), 256, 0, stream>>>(W3,  256, 256, Wc3th, Wc3tl, 512, 0);
    wsplit_t_kernel<<<CDIV(256 * 256, 256), 256, 0, stream>>>(Wr2, 256, 256, Wc3th, Wc3tl, 512, 256);
    wsplit_t_kernel<<<CDIV(256 * 256, 256), 256, 0, stream>>>(attnW, 256, 256, aWth, aWtl, 256, 0);
    wsplit_t_kernel<<<CDIV(2048 * 256, 256), 256, 0, stream>>>(Wfp, 2048, 256, Wfpth, Wfptl, 2048, 0);
    bsum_kernel<<<1, 256, 0, stream>>>(b2, br1, bsum2, 256);
    bsum_kernel<<<1, 256, 0, stream>>>(b3, br2, bsum3, 256);
    long long txin = (long long)Nn * 64;
    f32_to_f16_kernel<<<CDIV(txin, 256), 256, 0, stream>>>(x, xf16, txin);

    const int MB = CDIV(Nn, 128);

    // ---- layer 1: agg0 = Agg(xf16); x1 = relu(agg0@W1+b1) -> x1f16 + Acat2[:,128:256] ----
    gcn_gather_kernel<64><<<Nn, 64, 0, stream>>>(xf16, 64, dinv, offv, csr_src, agg0h, agg0l, 64, 0);
    mfma_gemm_kernel<<<dim3(MB, 1), 256, 0, stream>>>(agg0h, agg0l, 64, W1th, W1tl, 64,
                                                      b1, nullptr, 0, Acat2h, Acat2l, 256, 128,
                                                      x1f16, 128, Nn, 64, 128, 1, 0);

    // ---- layer 2: agg1 = Agg(x1f16) -> Acat2[:,0:128]; x2 -> x2f16 + Acat3[:,256:512] ----
    gcn_gather_kernel<128><<<Nn, 128, 0, stream>>>(x1f16, 128, dinv, offv, csr_src,
                                                   Acat2h, Acat2l, 256, 0);
    mfma_gemm_kernel<<<dim3(MB, 2), 256, 0, stream>>>(Acat2h, Acat2l, 256, Wc2th, Wc2tl, 256,
                                                      bsum2, nullptr, 0, Acat3h, Acat3l, 512, 256,
                                                      x2f16, 256, Nn, 256, 256, 1, 0);

    // ---- layer 3: agg2 = Agg(x2f16) -> Acat3[:,0:256]; x3 -> x3 pair + x3f16 ----
    gcn_gather_kernel<256><<<Nn, 256, 0, stream>>>(x2f16, 256, dinv, offv, csr_src,
                                                   Acat3h, Acat3l, 512, 0);
    mfma_gemm_kernel<<<dim3(MB, 2), 256, 0, stream>>>(Acat3h, Acat3l, 512, Wc3th, Wc3tl, 512,
                                                      bsum3, nullptr, 0, x3h, x3l, 256, 0,
                                                      x3f16, 256, Nn, 512, 256, 1, 0);

    // ---- attention logits (Acat3 dead; logits overlays Acat3h) ----
    mfma_gemm_kernel<<<dim3(MB, 2), 256, 0, stream>>>(x3h, x3l, 256, aWth, aWtl, 256,
                                                      nullptr, logits, 256, nullptr, nullptr, 0, 0,
                                                      nullptr, 0, Nn, 256, 256, 0, 0);

    // ---- fp MLP (split-K x8; buffers overlay Acat3l) ----
    long long tfp = (long long)B * 2048;
    split_kernel<<<CDIV(tfp, 256), 256, 0, stream>>>(fpin, fpinh, fpinl, tfp);
    mfma_gemm_kernel<<<dim3(CDIV(B, 128), 2, 8), 256, 0, stream>>>(fpinh, fpinl, 2048, Wfpth, Wfptl, 2048,
                                                                   nullptr, part, 256, nullptr, nullptr, 0, 0,
                                                                   nullptr, 0, B, 2048, 256, 0, 256);
    reduce_fp_kernel<<<CDIV(B * 256, 256), 256, 0, stream>>>(part, bfp, fpb, B * 256, B * 256, 8);

    // ---- fg MLP (tiny, fp32 path) ----
    gemm_kernel<<<dim3(CDIV(B, 128), 2), 256, 0, stream>>>(fgin, Wfg, bfg, fgb, B, 167, 256, 1);

    // ---- fused softmax+pool + final ----
    softmaxpool_kernel<<<B, 256, 0, stream>>>(logits, x3f16, batch, pooled, Nn, B);
    final_kernel<<<CDIV(B, 4), 256, 0, stream>>>(pooled, fpb, fgb, Wfc, bfc, out, B);
}

// Round 9
// 698.038 us; speedup vs baseline: 4.7487x; 1.0885x over previous
//
#include <hip/hip_runtime.h>
#include <math.h>

#define CDIV(a,b) (((a)+(b)-1)/(b))

typedef __attribute__((ext_vector_type(8))) short bf16x8;
typedef __attribute__((ext_vector_type(4))) float f32x4;

__device__ inline unsigned short f2bf(float f) {           // RNE bf16
    unsigned int u = __float_as_uint(f);
    u += 0x7fffu + ((u >> 16) & 1u);
    return (unsigned short)(u >> 16);
}
__device__ inline float bf2f(unsigned short h) { return __uint_as_float(((unsigned int)h) << 16); }
__device__ inline unsigned short f2h(float f) {
    _Float16 h = (_Float16)f;
    return *(unsigned short*)&h;
}
__device__ inline float h2f(unsigned short u) {
    _Float16 h = *(_Float16*)&u;
    return (float)h;
}

// ---------------- degree / dinv ----------------
__global__ void deg_count_kernel(const int* __restrict__ dst, int* __restrict__ deg, int E) {
    int e = blockIdx.x * blockDim.x + threadIdx.x;
    if (e < E) atomicAdd(&deg[dst[e]], 1);
}

__global__ void dinv_kernel(const int* __restrict__ deg, float* __restrict__ dinv, int N) {
    int i = blockIdx.x * blockDim.x + threadIdx.x;
    if (i < N) dinv[i] = rsqrtf((float)deg[i] + 1.0f);
}

// ---------------- parallel scan: chunk sums -> scan chunks -> apply ----------------
__global__ void chunk_sum_kernel(const int* __restrict__ deg, int* __restrict__ csum, int N) {
    __shared__ int ws[4];
    int c = blockIdx.x, t = threadIdx.x;          // 256 threads
    int base = c * 1024;
    int s = 0;
    for (int i = t; i < 1024; i += 256) { int idx = base + i; s += (idx < N) ? deg[idx] : 0; }
    for (int o = 32; o; o >>= 1) s += __shfl_xor(s, o);
    if ((t & 63) == 0) ws[t >> 6] = s;
    __syncthreads();
    if (t == 0) csum[c] = ws[0] + ws[1] + ws[2] + ws[3];
}

__global__ void chunk_scan_kernel(int* __restrict__ csum, int nc) {   // 1 block, 64 threads
    int t = threadIdx.x;
    int v = (t < nc) ? csum[t] : 0;
    int x = v;
    #pragma unroll
    for (int o = 1; o < 64; o <<= 1) { int y = __shfl_up(x, o, 64); if (t >= o) x += y; }
    if (t < nc) csum[t] = x - v;                  // exclusive
}

__global__ void chunk_scan_apply_kernel(const int* __restrict__ deg, const int* __restrict__ cbase,
                                        int* __restrict__ off, int N, int E) {
    __shared__ int wsum[16];
    int c = blockIdx.x;
    int t = threadIdx.x;                          // 1024 threads
    int lane = t & 63, wid = t >> 6;
    int i = c * 1024 + t;
    int v = (i < N) ? deg[i] : 0;
    int x = v;
    #pragma unroll
    for (int o = 1; o < 64; o <<= 1) { int y = __shfl_up(x, o, 64); if (lane >= o) x += y; }
    if (lane == 63) wsum[wid] = x;
    __syncthreads();
    if (wid == 0) {
        int wv = (lane < 16) ? wsum[lane] : 0;
        #pragma unroll
        for (int o = 1; o < 16; o <<= 1) { int y = __shfl_up(wv, o, 64); if (lane >= o) wv += y; }
        if (lane < 16) wsum[lane] = wv;
    }
    __syncthreads();
    int wexcl = wid ? wsum[wid - 1] : 0;
    if (i < N) off[i] = cbase[c] + wexcl + x - v;
    if (i == N) off[N] = E;
}

// ---------------- CSR fill ----------------
__global__ void csr_fill_kernel(const int* __restrict__ src, const int* __restrict__ dst,
                                const int* __restrict__ off, int* __restrict__ pos,
                                int* __restrict__ csr_src, int E) {
    int e = blockIdx.x * blockDim.x + threadIdx.x;
    if (e >= E) return;
    int s = src[e], d = dst[e];
    int p = off[d] + atomicAdd(&pos[d], 1);
    csr_src[p] = s;
}

__global__ void f32_to_f16_kernel(const float* __restrict__ src, unsigned short* __restrict__ dst,
                                  long long total) {
    long long idx = (long long)blockIdx.x * blockDim.x + threadIdx.x;
    if (idx >= total) return;
    dst[idx] = f2h(src[idx]);
}

// ---------------- transpose-split weights: src[K][N] -> bf16 pair dst[col][koff+k] ----------------
__global__ void wsplit_t_kernel(const float* __restrict__ src, int K, int N,
                                unsigned short* __restrict__ dsth, unsigned short* __restrict__ dstl,
                                int ldt, int koff) {
    int idx = blockIdx.x * blockDim.x + threadIdx.x;
    if (idx >= K * N) return;
    int col = idx / K;
    int k = idx - col * K;
    float v = src[(size_t)k * N + col];
    unsigned short h = f2bf(v);
    size_t o = (size_t)col * ldt + koff + k;
    dsth[o] = h;
    dstl[o] = f2bf(v - bf2f(h));
}

__global__ void bsum_kernel(const float* __restrict__ a, const float* __restrict__ b,
                            float* __restrict__ dst, int n) {
    int j = blockIdx.x * blockDim.x + threadIdx.x;
    if (j < n) dst[j] = a[j] + b[j];
}

// ---------------- GCN aggregation (gather): fp16 in -> fp16 out ----------------
template<int F>
__global__ __launch_bounds__(F) void gcn_gather_kernel(
        const unsigned short* __restrict__ h16, int ldh, int cofh,
        const float* __restrict__ dinv, const int* __restrict__ off,
        const int* __restrict__ csr_src,
        unsigned short* __restrict__ out16, int ldo, int cofo) {
    const int n = blockIdx.x;
    const int j = threadIdx.x;
    float dd = dinv[n];
    float acc = h2f(h16[(size_t)n * ldh + cofh + j]) * dd * dd;
    const int e1 = off[n + 1];
    int e = off[n];
    for (; e + 4 <= e1; e += 4) {
        int s0 = csr_src[e], s1 = csr_src[e + 1], s2 = csr_src[e + 2], s3 = csr_src[e + 3];
        float n0 = dinv[s0] * dd, n1 = dinv[s1] * dd, n2 = dinv[s2] * dd, n3 = dinv[s3] * dd;
        float h0 = h2f(h16[(size_t)s0 * ldh + cofh + j]);
        float h1 = h2f(h16[(size_t)s1 * ldh + cofh + j]);
        float h2 = h2f(h16[(size_t)s2 * ldh + cofh + j]);
        float h3 = h2f(h16[(size_t)s3 * ldh + cofh + j]);
        acc += h0 * n0; acc += h1 * n1; acc += h2 * n2; acc += h3 * n3;
    }
    for (; e < e1; ++e) {
        int s0 = csr_src[e];
        acc += h2f(h16[(size_t)s0 * ldh + cofh + j]) * (dinv[s0] * dd);
    }
    out16[(size_t)n * ldo + cofo + j] = f2h(acc);
}

// ---------------- split-bf16 MFMA GEMM; A = fp16 single, split exactly at staging ----------------
// A: [M][lda] fp16; Wt: bf16 pair [col][ldt]. Out: optional f32 C (ldc,+zoff), optional fp16 (ldo16,cof16).
__global__ __launch_bounds__(256) void mfma_gemm_kernel(
        const unsigned short* __restrict__ Af16, int lda,
        const unsigned short* __restrict__ Wth, const unsigned short* __restrict__ Wtl, int ldt,
        const float* __restrict__ bias,
        float* __restrict__ Cf32, int ldc,
        unsigned short* __restrict__ outf16, int ldo16, int cof16,
        int M, int K, int NW, int relu, int kchunk) {
    __shared__ unsigned short AsH[128 * 40];
    __shared__ unsigned short AsL[128 * 40];
    __shared__ unsigned short WsH[128 * 40];
    __shared__ unsigned short WsL[128 * 40];
    const int tid = threadIdx.x;
    const int row0 = blockIdx.x * 128;
    const int col0 = blockIdx.y * 128;
    int kbeg = 0, kend = K;
    size_t zoff = 0;
    if (kchunk) {
        kbeg = blockIdx.z * kchunk;
        kend = kbeg + kchunk;
        zoff = (size_t)blockIdx.z * M * NW;
    }
    const int w = tid >> 6, l = tid & 63;
    const int wm = w >> 1, wn = w & 1;
    const int lrow = l & 15, lk = l >> 4;
    f32x4 acc[4][4] = {};
    for (int k0 = kbeg; k0 < kend; k0 += 32) {
        // stage A: fp16 -> exact bf16 hi/lo split
        #pragma unroll
        for (int i = 0; i < 2; ++i) {
            int c = tid * 2 + i;              // 0..511
            int r = c >> 2, kq = c & 3;
            int gr = row0 + r;
            uint4 va = make_uint4(0, 0, 0, 0);
            if (gr < M) va = *(const uint4*)&Af16[(size_t)gr * lda + k0 + kq * 8];
            union { unsigned short us[8]; uint4 v; } hb, lb;
            const unsigned short* pu = (const unsigned short*)&va;
            #pragma unroll
            for (int q = 0; q < 8; ++q) {
                float f = h2f(pu[q]);
                unsigned int uf = __float_as_uint(f);
                hb.us[q] = (unsigned short)(uf >> 16);
                float r2 = f - __uint_as_float(uf & 0xFFFF0000u);
                lb.us[q] = (unsigned short)(__float_as_uint(r2) >> 16);
            }
            *(uint4*)&AsH[r * 40 + kq * 8] = hb.v;
            *(uint4*)&AsL[r * 40 + kq * 8] = lb.v;
        }
        // stage W pair (pre-split, transposed)
        #pragma unroll
        for (int i = 0; i < 2; ++i) {
            int c = tid + i * 256;            // 0..511
            int col = c & 127, kq = c >> 7;
            size_t g = (size_t)(col0 + col) * ldt + k0 + kq * 8;
            uint4 vh = *(const uint4*)&Wth[g];
            uint4 vl = *(const uint4*)&Wtl[g];
            *(uint4*)&WsH[col * 40 + kq * 8] = vh;
            *(uint4*)&WsL[col * 40 + kq * 8] = vl;
        }
        __syncthreads();
        bf16x8 aH[4], aL[4], bH[4], bL[4];
        #pragma unroll
        for (int mi = 0; mi < 4; ++mi) {
            int r = wm * 64 + mi * 16 + lrow;
            aH[mi] = *(const bf16x8*)&AsH[r * 40 + lk * 8];
            aL[mi] = *(const bf16x8*)&AsL[r * 40 + lk * 8];
        }
        #pragma unroll
        for (int ni = 0; ni < 4; ++ni) {
            int cc = wn * 64 + ni * 16 + lrow;
            bH[ni] = *(const bf16x8*)&WsH[cc * 40 + lk * 8];
            bL[ni] = *(const bf16x8*)&WsL[cc * 40 + lk * 8];
        }
        #pragma unroll
        for (int mi = 0; mi < 4; ++mi)
            #pragma unroll
            for (int ni = 0; ni < 4; ++ni) {
                acc[mi][ni] = __builtin_amdgcn_mfma_f32_16x16x32_bf16(aH[mi], bH[ni], acc[mi][ni], 0, 0, 0);
                acc[mi][ni] = __builtin_amdgcn_mfma_f32_16x16x32_bf16(aH[mi], bL[ni], acc[mi][ni], 0, 0, 0);
                acc[mi][ni] = __builtin_amdgcn_mfma_f32_16x16x32_bf16(aL[mi], bH[ni], acc[mi][ni], 0, 0, 0);
            }
        __syncthreads();
    }
    #pragma unroll
    for (int mi = 0; mi < 4; ++mi) {
        #pragma unroll
        for (int ni = 0; ni < 4; ++ni) {
            int gc = col0 + wn * 64 + ni * 16 + lrow;
            float bb = bias ? bias[gc] : 0.f;
            #pragma unroll
            for (int q = 0; q < 4; ++q) {
                int gr = row0 + wm * 64 + mi * 16 + lk * 4 + q;
                if (gr >= M) continue;
                float v = acc[mi][ni][q] + bb;
                if (relu) v = fmaxf(v, 0.f);
                if (Cf32) Cf32[zoff + (size_t)gr * ldc + gc] = v;
                if (outf16) outf16[(size_t)gr * ldo16 + cof16 + gc] = f2h(v);
            }
        }
    }
}

// ---------------- reduce split-K partials + bias + relu ----------------
__global__ void reduce_fp_kernel(const float* __restrict__ part, const float* __restrict__ bias,
                                 float* __restrict__ outp, int total, int stride, int nz) {
    int idx = blockIdx.x * blockDim.x + threadIdx.x;
    if (idx >= total) return;
    float s = 0.f;
    for (int z = 0; z < nz; ++z) s += part[(size_t)z * stride + idx];
    outp[idx] = fmaxf(s + bias[idx & 255], 0.f);
}

// ---------------- fp32 GEMM (tiny fg matmul, K=167) ----------------
__global__ __launch_bounds__(256) void gemm_kernel(
        const float* __restrict__ A, const float* __restrict__ W,
        const float* __restrict__ bias, float* __restrict__ C,
        int M, int K, int N, int do_relu) {
    __shared__ float As[16][128];
    __shared__ float Ws[16][128];
    const int tid = threadIdx.x;
    const int tx = tid & 15;
    const int ty = tid >> 4;
    const int row0 = blockIdx.x * 128;
    const int col0 = blockIdx.y * 128;
    float acc[8][8] = {};
    for (int k0 = 0; k0 < K; k0 += 16) {
        #pragma unroll
        for (int i = 0; i < 2; ++i) {
            int s = tid * 2 + i;
            int r = s >> 2, c = (s & 3) << 2;
            int gr = row0 + r;
            float4 v = make_float4(0.f, 0.f, 0.f, 0.f);
            if (gr < M) {
                if (k0 + c + 3 < K) {
                    v = *(const float4*)(A + (size_t)gr * K + k0 + c);
                } else {
                    float t0 = (k0 + c     < K) ? A[(size_t)gr * K + k0 + c    ] : 0.f;
                    float t1 = (k0 + c + 1 < K) ? A[(size_t)gr * K + k0 + c + 1] : 0.f;
                    float t2 = (k0 + c + 2 < K) ? A[(size_t)gr * K + k0 + c + 2] : 0.f;
                    float t3 = (k0 + c + 3 < K) ? A[(size_t)gr * K + k0 + c + 3] : 0.f;
                    v = make_float4(t0, t1, t2, t3);
                }
            }
            As[c + 0][r] = v.x; As[c + 1][r] = v.y; As[c + 2][r] = v.z; As[c + 3][r] = v.w;
        }
        #pragma unroll
        for (int i = 0; i < 2; ++i) {
            int s = tid * 2 + i;
            int kk = s >> 5, c = (s & 31) << 2;
            int gk = k0 + kk, gc = col0 + c;
            float4 v = make_float4(0.f, 0.f, 0.f, 0.f);
            if (gk < K && gc + 3 < N) v = *(const float4*)(W + (size_t)gk * N + gc);
            *(float4*)&Ws[kk][c] = v;
        }
        __syncthreads();
        #pragma unroll
        for (int kk = 0; kk < 16; ++kk) {
            float a[8], b[8];
            *(float4*)&a[0] = *(const float4*)&As[kk][ty * 4];
            *(float4*)&a[4] = *(const float4*)&As[kk][ty * 4 + 64];
            *(float4*)&b[0] = *(const float4*)&Ws[kk][tx * 4];
            *(float4*)&b[4] = *(const float4*)&Ws[kk][tx * 4 + 64];
            #pragma unroll
            for (int i2 = 0; i2 < 8; ++i2)
                #pragma unroll
                for (int j2 = 0; j2 < 8; ++j2)
                    acc[i2][j2] += a[i2] * b[j2];
        }
        __syncthreads();
    }
    #pragma unroll
    for (int rh = 0; rh < 2; ++rh)
        #pragma unroll
        for (int ii = 0; ii < 4; ++ii) {
            int gr = row0 + ty * 4 + rh * 64 + ii;
            if (gr >= M) continue;
            #pragma unroll
            for (int ch = 0; ch < 2; ++ch) {
                int gc = col0 + tx * 4 + ch * 64;
                float v[4];
                #pragma unroll
                for (int q = 0; q < 4; ++q) {
                    v[q] = acc[rh * 4 + ii][ch * 4 + q] + (bias ? bias[gc + q] : 0.f);
                    if (do_relu) v[q] = fmaxf(v[q], 0.f);
                }
                if (gc + 3 < N)
                    *(float4*)(C + (size_t)gr * N + gc) = make_float4(v[0], v[1], v[2], v[3]);
            }
        }
}

// ---------------- fused softmax + mean-pool (batch sorted) ----------------
__global__ __launch_bounds__(256) void softmaxpool_kernel(
        const float* __restrict__ logits, const unsigned short* __restrict__ x3f16,
        const int* __restrict__ batch, float* __restrict__ pooled, int N, int B) {
    __shared__ float lacc[4][256];
    const int b = blockIdx.x;
    const int t = threadIdx.x;
    const int lane = t & 63, wid = t >> 6;
    int lo = 0, hi = N;
    while (lo < hi) { int m = (lo + hi) >> 1; if (batch[m] < b) lo = m + 1; else hi = m; }
    int s0 = lo;
    hi = N;
    while (lo < hi) { int m = (lo + hi) >> 1; if (batch[m] <= b) lo = m + 1; else hi = m; }
    int s1 = lo;
    float a0 = 0.f, a1 = 0.f, a2 = 0.f, a3 = 0.f;
    for (int n = s0 + wid; n < s1; n += 4) {
        const float* p = logits + (size_t)n * 256;
        float v0 = p[lane], v1 = p[lane + 64], v2 = p[lane + 128], v3 = p[lane + 192];
        float m = fmaxf(fmaxf(v0, v1), fmaxf(v2, v3));
        for (int o = 32; o; o >>= 1) m = fmaxf(m, __shfl_xor(m, o));
        v0 = expf(v0 - m); v1 = expf(v1 - m); v2 = expf(v2 - m); v3 = expf(v3 - m);
        float s = v0 + v1 + v2 + v3;
        for (int o = 32; o; o >>= 1) s += __shfl_xor(s, o);
        float inv = 1.0f / s;
        const unsigned short* q = x3f16 + (size_t)n * 256;
        a0 += v0 * inv * h2f(q[lane]);
        a1 += v1 * inv * h2f(q[lane + 64]);
        a2 += v2 * inv * h2f(q[lane + 128]);
        a3 += v3 * inv * h2f(q[lane + 192]);
    }
    lacc[wid][lane] = a0; lacc[wid][lane + 64] = a1;
    lacc[wid][lane + 128] = a2; lacc[wid][lane + 192] = a3;
    __syncthreads();
    float tot = lacc[0][t] + lacc[1][t] + lacc[2][t] + lacc[3][t];
    float invc = 1.0f / fmaxf((float)(s1 - s0), 1.0f);
    pooled[(size_t)b * 256 + t] = tot * invc;
}

// ---------------- final ----------------
__global__ void final_kernel(const float* __restrict__ pooled, const float* __restrict__ fp,
                             const float* __restrict__ fg, const float* __restrict__ Wfc,
                             const float* __restrict__ bfc, float* __restrict__ out, int B) {
    int b = blockIdx.x * 4 + (threadIdx.x >> 6);
    int lane = threadIdx.x & 63;
    if (b >= B) return;
    float acc = 0.0f;
    #pragma unroll
    for (int i = 0; i < 4; ++i) {
        int j = lane + i * 64;
        size_t o = (size_t)b * 256 + j;
        acc += (pooled[o] + fp[o] + fg[o]) * Wfc[j];
    }
    for (int off = 32; off; off >>= 1) acc += __shfl_xor(acc, off);
    if (lane == 0) out[b] = acc + bfc[0];
}

extern "C" void kernel_launch(void* const* d_in, const int* in_sizes, int n_in,
                              void* d_out, int out_size, void* d_ws, size_t ws_size,
                              hipStream_t stream) {
    const float* x     = (const float*)d_in[0];
    const int*   ei    = (const int*)d_in[1];
    const int*   batch = (const int*)d_in[2];
    const float* fpin  = (const float*)d_in[3];
    const float* fgin  = (const float*)d_in[4];
    const float* W1  = (const float*)d_in[5];  const float* b1  = (const float*)d_in[6];
    const float* W2  = (const float*)d_in[7];  const float* b2  = (const float*)d_in[8];
    const float* W3  = (const float*)d_in[9];  const float* b3  = (const float*)d_in[10];
    const float* Wr1 = (const float*)d_in[11]; const float* br1 = (const float*)d_in[12];
    const float* Wr2 = (const float*)d_in[13]; const float* br2 = (const float*)d_in[14];
    const float* Wfp = (const float*)d_in[15]; const float* bfp = (const float*)d_in[16];
    const float* Wfg = (const float*)d_in[17]; const float* bfg = (const float*)d_in[18];
    const float* attnW = (const float*)d_in[19];
    const float* Wfc = (const float*)d_in[20]; const float* bfc = (const float*)d_in[21];
    float* out = (float*)d_out;

    const int Nn = in_sizes[0] / 64;
    const int E  = in_sizes[1] / 2;
    const int B  = in_sizes[3] / 2048;
    const int* src = ei;
    const int* dst = ei + E;

    char* wsb = (char*)d_ws;
    size_t woff = 0;
    auto alloc = [&](size_t bytes) -> void* {
        void* p = wsb + woff;
        woff += (bytes + 255) & ~(size_t)255;
        return p;
    };

    // ---- persistent ----
    int*   deg_i   = (int*)alloc((size_t)Nn * 4);
    int*   pos     = (int*)alloc((size_t)Nn * 4);
    int*   offv    = (int*)alloc(((size_t)Nn + 1) * 4);
    float* dinv    = (float*)alloc((size_t)Nn * 4);
    int*   csum    = (int*)alloc(64 * 4);
    int*   csr_src = (int*)alloc((size_t)E * 4);
    unsigned short* W1th  = (unsigned short*)alloc(64 * 128 * 2);
    unsigned short* W1tl  = (unsigned short*)alloc(64 * 128 * 2);
    unsigned short* Wc2th = (unsigned short*)alloc(256 * 256 * 2);
    unsigned short* Wc2tl = (unsigned short*)alloc(256 * 256 * 2);
    unsigned short* Wc3th = (unsigned short*)alloc(512 * 256 * 2);
    unsigned short* Wc3tl = (unsigned short*)alloc(512 * 256 * 2);
    unsigned short* aWth  = (unsigned short*)alloc(256 * 256 * 2);
    unsigned short* aWtl  = (unsigned short*)alloc(256 * 256 * 2);
    unsigned short* Wfpth = (unsigned short*)alloc(2048 * 256 * 2);
    unsigned short* Wfptl = (unsigned short*)alloc(2048 * 256 * 2);
    float* bsum2 = (float*)alloc(256 * 4);
    float* bsum3 = (float*)alloc(256 * 4);
    // ---- activation regions (single fp16) ----
    unsigned short* Acat2f16 = (unsigned short*)alloc((size_t)Nn * 256 * 2);  // 25.6 MB
    unsigned short* Acat3f16 = (unsigned short*)alloc((size_t)Nn * 512 * 2);  // 51.2 MB
    unsigned short* x3f16    = (unsigned short*)alloc((size_t)Nn * 256 * 2);  // 25.6 MB
    (void)ws_size; (void)n_in; (void)out_size;

    // ---- overlays ----
    // Acat3f16 head is dead until L2 GEMM: holds xf16 + agg0f16
    unsigned short* agg0f16 = Acat3f16;
    unsigned short* xf16    = (unsigned short*)((char*)Acat3f16 + 8388608);
    // after L3 GEMM, Acat3f16 dead: f32 logits (Nn*256*4 = 51.2 MB) overlays it
    float* logits = (float*)Acat3f16;
    // after L2 GEMM, Acat2f16 dead: fp-MLP buffers overlay it
    char* fpRegion = (char*)Acat2f16;
    unsigned short* fpin16 = (unsigned short*)(fpRegion);                // B*2048*2 = 4.19 MB
    float* part   = (float*)(fpRegion + 4718592);                        // 8*B*256*4 = 8.39 MB
    float* fpb    = (float*)(fpRegion + 13631488);
    float* fgb    = (float*)(fpRegion + 14680064);
    float* pooled = (float*)(fpRegion + 15728640);

    // ---- CSR build (parallel scan) ----
    hipMemsetAsync(deg_i, 0, (size_t)Nn * 4, stream);
    hipMemsetAsync(pos,   0, (size_t)Nn * 4, stream);
    deg_count_kernel<<<CDIV(E, 256), 256, 0, stream>>>(dst, deg_i, E);
    dinv_kernel<<<CDIV(Nn, 256), 256, 0, stream>>>(deg_i, dinv, Nn);
    const int NC = CDIV(Nn, 1024);
    chunk_sum_kernel<<<NC, 256, 0, stream>>>(deg_i, csum, Nn);
    chunk_scan_kernel<<<1, 64, 0, stream>>>(csum, NC);
    chunk_scan_apply_kernel<<<NC, 1024, 0, stream>>>(deg_i, csum, offv, Nn, E);
    csr_fill_kernel<<<CDIV(E, 256), 256, 0, stream>>>(src, dst, offv, pos, csr_src, E);

    // ---- weight transpose-splits + input conversion ----
    wsplit_t_kernel<<<CDIV(64 * 128, 256), 256, 0, stream>>>(W1, 64, 128, W1th, W1tl, 64, 0);
    wsplit_t_kernel<<<CDIV(128 * 256, 256), 256, 0, stream>>>(W2,  128, 256, Wc2th, Wc2tl, 256, 0);
    wsplit_t_kernel<<<CDIV(128 * 256, 256), 256, 0, stream>>>(Wr1, 128, 256, Wc2th, Wc2tl, 256, 128);
    wsplit_t_kernel<<<CDIV(256 * 256, 256), 256, 0, stream>>>(W3,  256, 256, Wc3th, Wc3tl, 512, 0);
    wsplit_t_kernel<<<CDIV(256 * 256, 256), 256, 0, stream>>>(Wr2, 256, 256, Wc3th, Wc3tl, 512, 256);
    wsplit_t_kernel<<<CDIV(256 * 256, 256), 256, 0, stream>>>(attnW, 256, 256, aWth, aWtl, 256, 0);
    wsplit_t_kernel<<<CDIV(2048 * 256, 256), 256, 0, stream>>>(Wfp, 2048, 256, Wfpth, Wfptl, 2048, 0);
    bsum_kernel<<<1, 256, 0, stream>>>(b2, br1, bsum2, 256);
    bsum_kernel<<<1, 256, 0, stream>>>(b3, br2, bsum3, 256);
    long long txin = (long long)Nn * 64;
    f32_to_f16_kernel<<<CDIV(txin, 256), 256, 0, stream>>>(x, xf16, txin);

    const int MB = CDIV(Nn, 128);

    // ---- layer 1: agg0 = Agg(xf16); x1 = relu(agg0@W1+b1) -> Acat2f16[:,128:256] ----
    gcn_gather_kernel<64><<<Nn, 64, 0, stream>>>(xf16, 64, 0, dinv, offv, csr_src, agg0f16, 64, 0);
    mfma_gemm_kernel<<<dim3(MB, 1), 256, 0, stream>>>(agg0f16, 64, W1th, W1tl, 64,
                                                      b1, nullptr, 0, Acat2f16, 256, 128,
                                                      Nn, 64, 128, 1, 0);

    // ---- layer 2: agg1 -> Acat2f16[:,0:128]; x2 = relu(Acat2@[W2;Wr1]+bsum2) -> Acat3f16[:,256:512] ----
    gcn_gather_kernel<128><<<Nn, 128, 0, stream>>>(Acat2f16, 256, 128, dinv, offv, csr_src,
                                                   Acat2f16, 256, 0);
    mfma_gemm_kernel<<<dim3(MB, 2), 256, 0, stream>>>(Acat2f16, 256, Wc2th, Wc2tl, 256,
                                                      bsum2, nullptr, 0, Acat3f16, 512, 256,
                                                      Nn, 256, 256, 1, 0);

    // ---- layer 3: agg2 -> Acat3f16[:,0:256]; x3 = relu(Acat3@[W3;Wr2]+bsum3) -> x3f16 ----
    gcn_gather_kernel<256><<<Nn, 256, 0, stream>>>(Acat3f16, 512, 256, dinv, offv, csr_src,
                                                   Acat3f16, 512, 0);
    mfma_gemm_kernel<<<dim3(MB, 2), 256, 0, stream>>>(Acat3f16, 512, Wc3th, Wc3tl, 512,
                                                      bsum3, nullptr, 0, x3f16, 256, 0,
                                                      Nn, 512, 256, 1, 0);

    // ---- attention logits (Acat3 dead; logits f32 overlays it) ----
    mfma_gemm_kernel<<<dim3(MB, 2), 256, 0, stream>>>(x3f16, 256, aWth, aWtl, 256,
                                                      nullptr, logits, 256, nullptr, 0, 0,
                                                      Nn, 256, 256, 0, 0);

    // ---- fp MLP (split-K x8; buffers overlay Acat2f16) ----
    long long tfp = (long long)B * 2048;
    f32_to_f16_kernel<<<CDIV(tfp, 256), 256, 0, stream>>>(fpin, fpin16, tfp);
    mfma_gemm_kernel<<<dim3(CDIV(B, 128), 2, 8), 256, 0, stream>>>(fpin16, 2048, Wfpth, Wfptl, 2048,
                                                                   nullptr, part, 256, nullptr, 0, 0,
                                                                   B, 2048, 256, 0, 256);
    reduce_fp_kernel<<<CDIV(B * 256, 256), 256, 0, stream>>>(part, bfp, fpb, B * 256, B * 256, 8);

    // ---- fg MLP (tiny, fp32 path) ----
    gemm_kernel<<<dim3(CDIV(B, 128), 2), 256, 0, stream>>>(fgin, Wfg, bfg, fgb, B, 167, 256, 1);

    // ---- fused softmax+pool + final ----
    softmaxpool_kernel<<<B, 256, 0, stream>>>(logits, x3f16, batch, pooled, Nn, B);
    final_kernel<<<CDIV(B, 4), 256, 0, stream>>>(pooled, fpb, fgb, Wfc, bfc, out, B);
}

// Round 10
// 684.168 us; speedup vs baseline: 4.8449x; 1.0203x over previous
//
#include <hip/hip_runtime.h>
#include <math.h>

#define CDIV(a,b) (((a)+(b)-1)/(b))

typedef __attribute__((ext_vector_type(8))) _Float16 f16x8;
typedef __attribute__((ext_vector_type(4))) float f32x4;

__device__ inline unsigned short f2h(float f) {
    _Float16 h = (_Float16)f;
    return *(unsigned short*)&h;
}
__device__ inline float h2f(unsigned short u) {
    _Float16 h = *(_Float16*)&u;
    return (float)h;
}

// ---------------- degree / dinv ----------------
__global__ void deg_count_kernel(const int* __restrict__ dst, int* __restrict__ deg, int E) {
    int e = blockIdx.x * blockDim.x + threadIdx.x;
    if (e < E) atomicAdd(&deg[dst[e]], 1);
}

__global__ void dinv_kernel(const int* __restrict__ deg, float* __restrict__ dinv, int N) {
    int i = blockIdx.x * blockDim.x + threadIdx.x;
    if (i < N) dinv[i] = rsqrtf((float)deg[i] + 1.0f);
}

// ---------------- parallel scan: chunk sums -> scan chunks -> apply ----------------
__global__ void chunk_sum_kernel(const int* __restrict__ deg, int* __restrict__ csum, int N) {
    __shared__ int ws[4];
    int c = blockIdx.x, t = threadIdx.x;          // 256 threads
    int base = c * 1024;
    int s = 0;
    for (int i = t; i < 1024; i += 256) { int idx = base + i; s += (idx < N) ? deg[idx] : 0; }
    for (int o = 32; o; o >>= 1) s += __shfl_xor(s, o);
    if ((t & 63) == 0) ws[t >> 6] = s;
    __syncthreads();
    if (t == 0) csum[c] = ws[0] + ws[1] + ws[2] + ws[3];
}

__global__ void chunk_scan_kernel(int* __restrict__ csum, int nc) {   // 1 block, 64 threads
    int t = threadIdx.x;
    int v = (t < nc) ? csum[t] : 0;
    int x = v;
    #pragma unroll
    for (int o = 1; o < 64; o <<= 1) { int y = __shfl_up(x, o, 64); if (t >= o) x += y; }
    if (t < nc) csum[t] = x - v;                  // exclusive
}

__global__ void chunk_scan_apply_kernel(const int* __restrict__ deg, const int* __restrict__ cbase,
                                        int* __restrict__ off, int N, int E) {
    __shared__ int wsum[16];
    int c = blockIdx.x;
    int t = threadIdx.x;                          // 1024 threads
    int lane = t & 63, wid = t >> 6;
    int i = c * 1024 + t;
    int v = (i < N) ? deg[i] : 0;
    int x = v;
    #pragma unroll
    for (int o = 1; o < 64; o <<= 1) { int y = __shfl_up(x, o, 64); if (lane >= o) x += y; }
    if (lane == 63) wsum[wid] = x;
    __syncthreads();
    if (wid == 0) {
        int wv = (lane < 16) ? wsum[lane] : 0;
        #pragma unroll
        for (int o = 1; o < 16; o <<= 1) { int y = __shfl_up(wv, o, 64); if (lane >= o) wv += y; }
        if (lane < 16) wsum[lane] = wv;
    }
    __syncthreads();
    int wexcl = wid ? wsum[wid - 1] : 0;
    if (i < N) off[i] = cbase[c] + wexcl + x - v;
    if (i == N) off[N] = E;
}

// ---------------- CSR fill ----------------
__global__ void csr_fill_kernel(const int* __restrict__ src, const int* __restrict__ dst,
                                const int* __restrict__ off, int* __restrict__ pos,
                                int* __restrict__ csr_src, int E) {
    int e = blockIdx.x * blockDim.x + threadIdx.x;
    if (e >= E) return;
    int s = src[e], d = dst[e];
    int p = off[d] + atomicAdd(&pos[d], 1);
    csr_src[p] = s;
}

__global__ void f32_to_f16_kernel(const float* __restrict__ src, unsigned short* __restrict__ dst,
                                  long long total) {
    long long idx = (long long)blockIdx.x * blockDim.x + threadIdx.x;
    if (idx >= total) return;
    dst[idx] = f2h(src[idx]);
}

// ---------------- transpose-split weights: src[K][N] -> fp16 pair dst[col][koff+k] ----------------
__global__ void wsplit_t_kernel(const float* __restrict__ src, int K, int N,
                                unsigned short* __restrict__ dsth, unsigned short* __restrict__ dstl,
                                int ldt, int koff) {
    int idx = blockIdx.x * blockDim.x + threadIdx.x;
    if (idx >= K * N) return;
    int col = idx / K;
    int k = idx - col * K;
    float v = src[(size_t)k * N + col];
    unsigned short h = f2h(v);
    size_t o = (size_t)col * ldt + koff + k;
    dsth[o] = h;
    dstl[o] = f2h(v - h2f(h));
}

__global__ void bsum_kernel(const float* __restrict__ a, const float* __restrict__ b,
                            float* __restrict__ dst, int n) {
    int j = blockIdx.x * blockDim.x + threadIdx.x;
    if (j < n) dst[j] = a[j] + b[j];
}

// ---------------- GCN aggregation (gather): fp16 in -> fp16 out ----------------
template<int F>
__global__ __launch_bounds__(F) void gcn_gather_kernel(
        const unsigned short* __restrict__ h16, int ldh, int cofh,
        const float* __restrict__ dinv, const int* __restrict__ off,
        const int* __restrict__ csr_src,
        unsigned short* __restrict__ out16, int ldo, int cofo) {
    const int n = blockIdx.x;
    const int j = threadIdx.x;
    float dd = dinv[n];
    float acc = h2f(h16[(size_t)n * ldh + cofh + j]) * dd * dd;
    const int e1 = off[n + 1];
    int e = off[n];
    for (; e + 4 <= e1; e += 4) {
        int s0 = csr_src[e], s1 = csr_src[e + 1], s2 = csr_src[e + 2], s3 = csr_src[e + 3];
        float n0 = dinv[s0] * dd, n1 = dinv[s1] * dd, n2 = dinv[s2] * dd, n3 = dinv[s3] * dd;
        float h0 = h2f(h16[(size_t)s0 * ldh + cofh + j]);
        float h1 = h2f(h16[(size_t)s1 * ldh + cofh + j]);
        float h2 = h2f(h16[(size_t)s2 * ldh + cofh + j]);
        float h3 = h2f(h16[(size_t)s3 * ldh + cofh + j]);
        acc += h0 * n0; acc += h1 * n1; acc += h2 * n2; acc += h3 * n3;
    }
    for (; e < e1; ++e) {
        int s0 = csr_src[e];
        acc += h2f(h16[(size_t)s0 * ldh + cofh + j]) * (dinv[s0] * dd);
    }
    out16[(size_t)n * ldo + cofo + j] = f2h(acc);
}

// ---------------- fp16 MFMA GEMM: C = A @ (Wh + Wl), 2-term, fp32 accumulate ----------------
// A: [M][lda] fp16 (exact); Wt: fp16 pair [col][ldt]. Out: optional f32 C, optional fp16.
__global__ __launch_bounds__(256) void mfma_gemm_kernel(
        const unsigned short* __restrict__ Af16, int lda,
        const unsigned short* __restrict__ Wth, const unsigned short* __restrict__ Wtl, int ldt,
        const float* __restrict__ bias,
        float* __restrict__ Cf32, int ldc,
        unsigned short* __restrict__ outf16, int ldo16, int cof16,
        int M, int K, int NW, int relu, int kchunk) {
    __shared__ unsigned short AsF[128 * 40];
    __shared__ unsigned short WsH[128 * 40];
    __shared__ unsigned short WsL[128 * 40];
    const int tid = threadIdx.x;
    const int row0 = blockIdx.x * 128;
    const int col0 = blockIdx.y * 128;
    int kbeg = 0, kend = K;
    size_t zoff = 0;
    if (kchunk) {
        kbeg = blockIdx.z * kchunk;
        kend = kbeg + kchunk;
        zoff = (size_t)blockIdx.z * M * NW;
    }
    const int w = tid >> 6, l = tid & 63;
    const int wm = w >> 1, wn = w & 1;
    const int lrow = l & 15, lk = l >> 4;
    f32x4 acc[4][4] = {};
    for (int k0 = kbeg; k0 < kend; k0 += 32) {
        // stage A (plain fp16 copy): 128 rows x 32 k = 8 KB -> 2 x 16B per thread
        #pragma unroll
        for (int i = 0; i < 2; ++i) {
            int c = tid * 2 + i;              // 0..511
            int r = c >> 2, kq = c & 3;
            int gr = row0 + r;
            uint4 va = make_uint4(0, 0, 0, 0);
            if (gr < M) va = *(const uint4*)&Af16[(size_t)gr * lda + k0 + kq * 8];
            *(uint4*)&AsF[r * 40 + kq * 8] = va;
        }
        // stage W pair (pre-split fp16, transposed): 2 x 8 KB -> 2 x 2 x 16B per thread
        #pragma unroll
        for (int i = 0; i < 2; ++i) {
            int c = tid + i * 256;            // 0..511
            int col = c & 127, kq = c >> 7;
            size_t g = (size_t)(col0 + col) * ldt + k0 + kq * 8;
            uint4 vh = *(const uint4*)&Wth[g];
            uint4 vl = *(const uint4*)&Wtl[g];
            *(uint4*)&WsH[col * 40 + kq * 8] = vh;
            *(uint4*)&WsL[col * 40 + kq * 8] = vl;
        }
        __syncthreads();
        f16x8 aF[4], bH[4], bL[4];
        #pragma unroll
        for (int mi = 0; mi < 4; ++mi) {
            int r = wm * 64 + mi * 16 + lrow;
            aF[mi] = *(const f16x8*)&AsF[r * 40 + lk * 8];
        }
        #pragma unroll
        for (int ni = 0; ni < 4; ++ni) {
            int cc = wn * 64 + ni * 16 + lrow;
            bH[ni] = *(const f16x8*)&WsH[cc * 40 + lk * 8];
            bL[ni] = *(const f16x8*)&WsL[cc * 40 + lk * 8];
        }
        #pragma unroll
        for (int mi = 0; mi < 4; ++mi)
            #pragma unroll
            for (int ni = 0; ni < 4; ++ni) {
                acc[mi][ni] = __builtin_amdgcn_mfma_f32_16x16x32_f16(aF[mi], bH[ni], acc[mi][ni], 0, 0, 0);
                acc[mi][ni] = __builtin_amdgcn_mfma_f32_16x16x32_f16(aF[mi], bL[ni], acc[mi][ni], 0, 0, 0);
            }
        __syncthreads();
    }
    #pragma unroll
    for (int mi = 0; mi < 4; ++mi) {
        #pragma unroll
        for (int ni = 0; ni < 4; ++ni) {
            int gc = col0 + wn * 64 + ni * 16 + lrow;
            float bb = bias ? bias[gc] : 0.f;
            #pragma unroll
            for (int q = 0; q < 4; ++q) {
                int gr = row0 + wm * 64 + mi * 16 + lk * 4 + q;
                if (gr >= M) continue;
                float v = acc[mi][ni][q] + bb;
                if (relu) v = fmaxf(v, 0.f);
                if (Cf32) Cf32[zoff + (size_t)gr * ldc + gc] = v;
                if (outf16) outf16[(size_t)gr * ldo16 + cof16 + gc] = f2h(v);
            }
        }
    }
}

// ---------------- reduce split-K partials + bias + relu ----------------
__global__ void reduce_fp_kernel(const float* __restrict__ part, const float* __restrict__ bias,
                                 float* __restrict__ outp, int total, int stride, int nz) {
    int idx = blockIdx.x * blockDim.x + threadIdx.x;
    if (idx >= total) return;
    float s = 0.f;
    for (int z = 0; z < nz; ++z) s += part[(size_t)z * stride + idx];
    outp[idx] = fmaxf(s + bias[idx & 255], 0.f);
}

// ---------------- fp32 GEMM (tiny fg matmul, K=167) ----------------
__global__ __launch_bounds__(256) void gemm_kernel(
        const float* __restrict__ A, const float* __restrict__ W,
        const float* __restrict__ bias, float* __restrict__ C,
        int M, int K, int N, int do_relu) {
    __shared__ float As[16][128];
    __shared__ float Ws[16][128];
    const int tid = threadIdx.x;
    const int tx = tid & 15;
    const int ty = tid >> 4;
    const int row0 = blockIdx.x * 128;
    const int col0 = blockIdx.y * 128;
    float acc[8][8] = {};
    for (int k0 = 0; k0 < K; k0 += 16) {
        #pragma unroll
        for (int i = 0; i < 2; ++i) {
            int s = tid * 2 + i;
            int r = s >> 2, c = (s & 3) << 2;
            int gr = row0 + r;
            float4 v = make_float4(0.f, 0.f, 0.f, 0.f);
            if (gr < M) {
                if (k0 + c + 3 < K) {
                    v = *(const float4*)(A + (size_t)gr * K + k0 + c);
                } else {
                    float t0 = (k0 + c     < K) ? A[(size_t)gr * K + k0 + c    ] : 0.f;
                    float t1 = (k0 + c + 1 < K) ? A[(size_t)gr * K + k0 + c + 1] : 0.f;
                    float t2 = (k0 + c + 2 < K) ? A[(size_t)gr * K + k0 + c + 2] : 0.f;
                    float t3 = (k0 + c + 3 < K) ? A[(size_t)gr * K + k0 + c + 3] : 0.f;
                    v = make_float4(t0, t1, t2, t3);
                }
            }
            As[c + 0][r] = v.x; As[c + 1][r] = v.y; As[c + 2][r] = v.z; As[c + 3][r] = v.w;
        }
        #pragma unroll
        for (int i = 0; i < 2; ++i) {
            int s = tid * 2 + i;
            int kk = s >> 5, c = (s & 31) << 2;
            int gk = k0 + kk, gc = col0 + c;
            float4 v = make_float4(0.f, 0.f, 0.f, 0.f);
            if (gk < K && gc + 3 < N) v = *(const float4*)(W + (size_t)gk * N + gc);
            *(float4*)&Ws[kk][c] = v;
        }
        __syncthreads();
        #pragma unroll
        for (int kk = 0; kk < 16; ++kk) {
            float a[8], b[8];
            *(float4*)&a[0] = *(const float4*)&As[kk][ty * 4];
            *(float4*)&a[4] = *(const float4*)&As[kk][ty * 4 + 64];
            *(float4*)&b[0] = *(const float4*)&Ws[kk][tx * 4];
            *(float4*)&b[4] = *(const float4*)&Ws[kk][tx * 4 + 64];
            #pragma unroll
            for (int i2 = 0; i2 < 8; ++i2)
                #pragma unroll
                for (int j2 = 0; j2 < 8; ++j2)
                    acc[i2][j2] += a[i2] * b[j2];
        }
        __syncthreads();
    }
    #pragma unroll
    for (int rh = 0; rh < 2; ++rh)
        #pragma unroll
        for (int ii = 0; ii < 4; ++ii) {
            int gr = row0 + ty * 4 + rh * 64 + ii;
            if (gr >= M) continue;
            #pragma unroll
            for (int ch = 0; ch < 2; ++ch) {
                int gc = col0 + tx * 4 + ch * 64;
                float v[4];
                #pragma unroll
                for (int q = 0; q < 4; ++q) {
                    v[q] = acc[rh * 4 + ii][ch * 4 + q] + (bias ? bias[gc + q] : 0.f);
                    if (do_relu) v[q] = fmaxf(v[q], 0.f);
                }
                if (gc + 3 < N)
                    *(float4*)(C + (size_t)gr * N + gc) = make_float4(v[0], v[1], v[2], v[3]);
            }
        }
}

// ---------------- fused softmax + mean-pool (batch sorted) ----------------
__global__ __launch_bounds__(256) void softmaxpool_kernel(
        const float* __restrict__ logits, const unsigned short* __restrict__ x3f16,
        const int* __restrict__ batch, float* __restrict__ pooled, int N, int B) {
    __shared__ float lacc[4][256];
    const int b = blockIdx.x;
    const int t = threadIdx.x;
    const int lane = t & 63, wid = t >> 6;
    int lo = 0, hi = N;
    while (lo < hi) { int m = (lo + hi) >> 1; if (batch[m] < b) lo = m + 1; else hi = m; }
    int s0 = lo;
    hi = N;
    while (lo < hi) { int m = (lo + hi) >> 1; if (batch[m] <= b) lo = m + 1; else hi = m; }
    int s1 = lo;
    float a0 = 0.f, a1 = 0.f, a2 = 0.f, a3 = 0.f;
    for (int n = s0 + wid; n < s1; n += 4) {
        const float* p = logits + (size_t)n * 256;
        float v0 = p[lane], v1 = p[lane + 64], v2 = p[lane + 128], v3 = p[lane + 192];
        float m = fmaxf(fmaxf(v0, v1), fmaxf(v2, v3));
        for (int o = 32; o; o >>= 1) m = fmaxf(m, __shfl_xor(m, o));
        v0 = expf(v0 - m); v1 = expf(v1 - m); v2 = expf(v2 - m); v3 = expf(v3 - m);
        float s = v0 + v1 + v2 + v3;
        for (int o = 32; o; o >>= 1) s += __shfl_xor(s, o);
        float inv = 1.0f / s;
        const unsigned short* q = x3f16 + (size_t)n * 256;
        a0 += v0 * inv * h2f(q[lane]);
        a1 += v1 * inv * h2f(q[lane + 64]);
        a2 += v2 * inv * h2f(q[lane + 128]);
        a3 += v3 * inv * h2f(q[lane + 192]);
    }
    lacc[wid][lane] = a0; lacc[wid][lane + 64] = a1;
    lacc[wid][lane + 128] = a2; lacc[wid][lane + 192] = a3;
    __syncthreads();
    float tot = lacc[0][t] + lacc[1][t] + lacc[2][t] + lacc[3][t];
    float invc = 1.0f / fmaxf((float)(s1 - s0), 1.0f);
    pooled[(size_t)b * 256 + t] = tot * invc;
}

// ---------------- final ----------------
__global__ void final_kernel(const float* __restrict__ pooled, const float* __restrict__ fp,
                             const float* __restrict__ fg, const float* __restrict__ Wfc,
                             const float* __restrict__ bfc, float* __restrict__ out, int B) {
    int b = blockIdx.x * 4 + (threadIdx.x >> 6);
    int lane = threadIdx.x & 63;
    if (b >= B) return;
    float acc = 0.0f;
    #pragma unroll
    for (int i = 0; i < 4; ++i) {
        int j = lane + i * 64;
        size_t o = (size_t)b * 256 + j;
        acc += (pooled[o] + fp[o] + fg[o]) * Wfc[j];
    }
    for (int off = 32; off; off >>= 1) acc += __shfl_xor(acc, off);
    if (lane == 0) out[b] = acc + bfc[0];
}

extern "C" void kernel_launch(void* const* d_in, const int* in_sizes, int n_in,
                              void* d_out, int out_size, void* d_ws, size_t ws_size,
                              hipStream_t stream) {
    const float* x     = (const float*)d_in[0];
    const int*   ei    = (const int*)d_in[1];
    const int*   batch = (const int*)d_in[2];
    const float* fpin  = (const float*)d_in[3];
    const float* fgin  = (const float*)d_in[4];
    const float* W1  = (const float*)d_in[5];  const float* b1  = (const float*)d_in[6];
    const float* W2  = (const float*)d_in[7];  const float* b2  = (const float*)d_in[8];
    const float* W3  = (const float*)d_in[9];  const float* b3  = (const float*)d_in[10];
    const float* Wr1 = (const float*)d_in[11]; const float* br1 = (const float*)d_in[12];
    const float* Wr2 = (const float*)d_in[13]; const float* br2 = (const float*)d_in[14];
    const float* Wfp = (const float*)d_in[15]; const float* bfp = (const float*)d_in[16];
    const float* Wfg = (const float*)d_in[17]; const float* bfg = (const float*)d_in[18];
    const float* attnW = (const float*)d_in[19];
    const float* Wfc = (const float*)d_in[20]; const float* bfc = (const float*)d_in[21];
    float* out = (float*)d_out;

    const int Nn = in_sizes[0] / 64;
    const int E  = in_sizes[1] / 2;
    const int B  = in_sizes[3] / 2048;
    const int* src = ei;
    const int* dst = ei + E;

    char* wsb = (char*)d_ws;
    size_t woff = 0;
    auto alloc = [&](size_t bytes) -> void* {
        void* p = wsb + woff;
        woff += (bytes + 255) & ~(size_t)255;
        return p;
    };

    // ---- persistent ----
    int*   deg_i   = (int*)alloc((size_t)Nn * 4);
    int*   pos     = (int*)alloc((size_t)Nn * 4);
    int*   offv    = (int*)alloc(((size_t)Nn + 1) * 4);
    float* dinv    = (float*)alloc((size_t)Nn * 4);
    int*   csum    = (int*)alloc(64 * 4);
    int*   csr_src = (int*)alloc((size_t)E * 4);
    unsigned short* W1th  = (unsigned short*)alloc(64 * 128 * 2);
    unsigned short* W1tl  = (unsigned short*)alloc(64 * 128 * 2);
    unsigned short* Wc2th = (unsigned short*)alloc(256 * 256 * 2);
    unsigned short* Wc2tl = (unsigned short*)alloc(256 * 256 * 2);
    unsigned short* Wc3th = (unsigned short*)alloc(512 * 256 * 2);
    unsigned short* Wc3tl = (unsigned short*)alloc(512 * 256 * 2);
    unsigned short* aWth  = (unsigned short*)alloc(256 * 256 * 2);
    unsigned short* aWtl  = (unsigned short*)alloc(256 * 256 * 2);
    unsigned short* Wfpth = (unsigned short*)alloc(2048 * 256 * 2);
    unsigned short* Wfptl = (unsigned short*)alloc(2048 * 256 * 2);
    float* bsum2 = (float*)alloc(256 * 4);
    float* bsum3 = (float*)alloc(256 * 4);
    // ---- activation regions (single fp16) ----
    unsigned short* Acat2f16 = (unsigned short*)alloc((size_t)Nn * 256 * 2);  // 25.6 MB
    unsigned short* Acat3f16 = (unsigned short*)alloc((size_t)Nn * 512 * 2);  // 51.2 MB
    unsigned short* x3f16    = (unsigned short*)alloc((size_t)Nn * 256 * 2);  // 25.6 MB
    (void)ws_size; (void)n_in; (void)out_size;

    // ---- overlays ----
    // Acat3f16 head is dead until L2 GEMM: holds xf16 + agg0f16
    unsigned short* agg0f16 = Acat3f16;
    unsigned short* xf16    = (unsigned short*)((char*)Acat3f16 + 8388608);
    // after L3 GEMM, Acat3f16 dead: f32 logits (Nn*256*4 = 51.2 MB) overlays it
    float* logits = (float*)Acat3f16;
    // after L2 GEMM, Acat2f16 dead: fp-MLP buffers overlay it
    char* fpRegion = (char*)Acat2f16;
    unsigned short* fpin16 = (unsigned short*)(fpRegion);                // B*2048*2 = 4.19 MB
    float* part   = (float*)(fpRegion + 4718592);                        // 8*B*256*4 = 8.39 MB
    float* fpb    = (float*)(fpRegion + 13631488);
    float* fgb    = (float*)(fpRegion + 14680064);
    float* pooled = (float*)(fpRegion + 15728640);

    // ---- CSR build (parallel scan) ----
    hipMemsetAsync(deg_i, 0, (size_t)Nn * 4, stream);
    hipMemsetAsync(pos,   0, (size_t)Nn * 4, stream);
    deg_count_kernel<<<CDIV(E, 256), 256, 0, stream>>>(dst, deg_i, E);
    dinv_kernel<<<CDIV(Nn, 256), 256, 0, stream>>>(deg_i, dinv, Nn);
    const int NC = CDIV(Nn, 1024);
    chunk_sum_kernel<<<NC, 256, 0, stream>>>(deg_i, csum, Nn);
    chunk_scan_kernel<<<1, 64, 0, stream>>>(csum, NC);
    chunk_scan_apply_kernel<<<NC, 1024, 0, stream>>>(deg_i, csum, offv, Nn, E);
    csr_fill_kernel<<<CDIV(E, 256), 256, 0, stream>>>(src, dst, offv, pos, csr_src, E);

    // ---- weight transpose-splits + input conversion ----
    wsplit_t_kernel<<<CDIV(64 * 128, 256), 256, 0, stream>>>(W1, 64, 128, W1th, W1tl, 64, 0);
    wsplit_t_kernel<<<CDIV(128 * 256, 256), 256, 0, stream>>>(W2,  128, 256, Wc2th, Wc2tl, 256, 0);
    wsplit_t_kernel<<<CDIV(128 * 256, 256), 256, 0, stream>>>(Wr1, 128, 256, Wc2th, Wc2tl, 256, 128);
    wsplit_t_kernel<<<CDIV(256 * 256, 256), 256, 0, stream>>>(W3,  256, 256, Wc3th, Wc3tl, 512, 0);
    wsplit_t_kernel<<<CDIV(256 * 256, 256), 256, 0, stream>>>(Wr2, 256, 256, Wc3th, Wc3tl, 512, 256);
    wsplit_t_kernel<<<CDIV(256 * 256, 256), 256, 0, stream>>>(attnW, 256, 256, aWth, aWtl, 256, 0);
    wsplit_t_kernel<<<CDIV(2048 * 256, 256), 256, 0, stream>>>(Wfp, 2048, 256, Wfpth, Wfptl, 2048, 0);
    bsum_kernel<<<1, 256, 0, stream>>>(b2, br1, bsum2, 256);
    bsum_kernel<<<1, 256, 0, stream>>>(b3, br2, bsum3, 256);
    long long txin = (long long)Nn * 64;
    f32_to_f16_kernel<<<CDIV(txin, 256), 256, 0, stream>>>(x, xf16, txin);

    const int MB = CDIV(Nn, 128);

    // ---- layer 1: agg0 = Agg(xf16); x1 = relu(agg0@W1+b1) -> Acat2f16[:,128:256] ----
    gcn_gather_kernel<64><<<Nn, 64, 0, stream>>>(xf16, 64, 0, dinv, offv, csr_src, agg0f16, 64, 0);
    mfma_gemm_kernel<<<dim3(MB, 1), 256, 0, stream>>>(agg0f16, 64, W1th, W1tl, 64,
                                                      b1, nullptr, 0, Acat2f16, 256, 128,
                                                      Nn, 64, 128, 1, 0);

    // ---- layer 2: agg1 -> Acat2f16[:,0:128]; x2 = relu(Acat2@[W2;Wr1]+bsum2) -> Acat3f16[:,256:512] ----
    gcn_gather_kernel<128><<<Nn, 128, 0, stream>>>(Acat2f16, 256, 128, dinv, offv, csr_src,
                                                   Acat2f16, 256, 0);
    mfma_gemm_kernel<<<dim3(MB, 2), 256, 0, stream>>>(Acat2f16, 256, Wc2th, Wc2tl, 256,
                                                      bsum2, nullptr, 0, Acat3f16, 512, 256,
                                                      Nn, 256, 256, 1, 0);

    // ---- layer 3: agg2 -> Acat3f16[:,0:256]; x3 = relu(Acat3@[W3;Wr2]+bsum3) -> x3f16 ----
    gcn_gather_kernel<256><<<Nn, 256, 0, stream>>>(Acat3f16, 512, 256, dinv, offv, csr_src,
                                                   Acat3f16, 512, 0);
    mfma_gemm_kernel<<<dim3(MB, 2), 256, 0, stream>>>(Acat3f16, 512, Wc3th, Wc3tl, 512,
                                                      bsum3, nullptr, 0, x3f16, 256, 0,
                                                      Nn, 512, 256, 1, 0);

    // ---- attention logits (Acat3 dead; logits f32 overlays it) ----
    mfma_gemm_kernel<<<dim3(MB, 2), 256, 0, stream>>>(x3f16, 256, aWth, aWtl, 256,
                                                      nullptr, logits, 256, nullptr, 0, 0,
                                                      Nn, 256, 256, 0, 0);

    // ---- fp MLP (split-K x8; buffers overlay Acat2f16) ----
    long long tfp = (long long)B * 2048;
    f32_to_f16_kernel<<<CDIV(tfp, 256), 256, 0, stream>>>(fpin, fpin16, tfp);
    mfma_gemm_kernel<<<dim3(CDIV(B, 128), 2, 8), 256, 0, stream>>>(fpin16, 2048, Wfpth, Wfptl, 2048,
                                                                   nullptr, part, 256, nullptr, 0, 0,
                                                                   B, 2048, 256, 0, 256);
    reduce_fp_kernel<<<CDIV(B * 256, 256), 256, 0, stream>>>(part, bfp, fpb, B * 256, B * 256, 8);

    // ---- fg MLP (tiny, fp32 path) ----
    gemm_kernel<<<dim3(CDIV(B, 128), 2), 256, 0, stream>>>(fgin, Wfg, bfg, fgb, B, 167, 256, 1);

    // ---- fused softmax+pool + final ----
    softmaxpool_kernel<<<B, 256, 0, stream>>>(logits, x3f16, batch, pooled, Nn, B);
    final_kernel<<<CDIV(B, 4), 256, 0, stream>>>(pooled, fpb, fgb, Wfc, bfc, out, B);
}